// Round 1
// 731.101 us; speedup vs baseline: 1.1383x; 1.1383x over previous
//
#include <hip/hip_runtime.h>
#include <hip/hip_bf16.h>

// RG-LRU forward, MI355X/gfx950.
// I/O dtype: fp32. Internally bf16 MFMA GEMMs, fp32 gate_a + fp32 scan state.
// R3: big GEMMs rewritten to the 256x256 8-phase counted-vmcnt template
// (T2 swizzle + T3/T4 deep pipeline + T5 setprio + T1 XCD swizzle), with an
// LDS-staged fully-coalesced C epilogue (kills partial-line write/RMW
// amplification seen as WRITE_SIZE 186MB vs 64/128MB ideal).

typedef unsigned short u16;
typedef unsigned int u32;
typedef unsigned long long u64;
typedef __attribute__((ext_vector_type(8))) short short8;
typedef __attribute__((ext_vector_type(4))) float floatx4;

#define DEV __device__ __forceinline__

DEV float bf2f(u16 u) { union { u32 i; float f; } v; v.i = ((u32)u) << 16; return v.f; }
DEV u16 f2bf(float f) {
  union { float f; u32 i; } v; v.f = f;
  u32 r = v.i + 0x7fffu + ((v.i >> 16) & 1u);  // RNE
  return (u16)(r >> 16);
}
DEV float sigmoidf_(float x) { return 1.f / (1.f + __expf(-x)); }

#if __has_builtin(__builtin_amdgcn_global_load_lds)
#define USE_ASYNC_LDS 1
#endif

DEV void cp16(const void* g, void* l) {
#if defined(USE_ASYNC_LDS) && defined(__HIP_DEVICE_COMPILE__)
  __builtin_amdgcn_global_load_lds((const __attribute__((address_space(1))) u32*)g,
                                   (__attribute__((address_space(3))) u32*)l, 16, 0, 0);
#else
  *(short8*)l = *(const short8*)g;
#endif
}
#define WAIT_VM() asm volatile("s_waitcnt vmcnt(0)" ::: "memory")

// ---------------------------------------------------------------- convert fp32 -> bf16
__global__ __launch_bounds__(256) void convert_f32_bf16(
    const float* __restrict__ src, u16* __restrict__ dst, long n) {
  long i = ((long)blockIdx.x * 256 + threadIdx.x) * 8;
  if (i >= n) return;
  float4 a = *(const float4*)(src + i);
  float4 b = *(const float4*)(src + i + 4);
  union { u16 u[8]; short8 v; } o;
  o.u[0] = f2bf(a.x); o.u[1] = f2bf(a.y); o.u[2] = f2bf(a.z); o.u[3] = f2bf(a.w);
  o.u[4] = f2bf(b.x); o.u[5] = f2bf(b.y); o.u[6] = f2bf(b.z); o.u[7] = f2bf(b.w);
  *(short8*)(dst + i) = o.v;
}

// ---------------------------------------------------------------- transpose + convert
// src: R x C row-major (fp32) -> dst: C x R row-major (bf16). batched via blockIdx.z.
__global__ __launch_bounds__(256) void transpose_f32_bf16(
    const float* __restrict__ src, u16* __restrict__ dst, int R, int C,
    long sBatch, long dBatch) {
  __shared__ u16 tile[32][33];
  const int n = blockIdx.z;
  src += (long)n * sBatch;
  dst += (long)n * dBatch;
  const int c0 = blockIdx.x * 32, r0 = blockIdx.y * 32;
  const int tx = threadIdx.x, ty = threadIdx.y;  // (32,8)
#pragma unroll
  for (int i = 0; i < 32; i += 8)
    tile[ty + i][tx] = f2bf(src[(long)(r0 + ty + i) * C + c0 + tx]);
  __syncthreads();
#pragma unroll
  for (int i = 0; i < 32; i += 8) dst[(long)(c0 + ty + i) * R + r0 + tx] = tile[tx][ty + i];
}

// ---------------------------------------------------------------- 256^2 8-phase GEMM
// C[M,N] = A[M,K] @ BT[N,K]^T + bias[N]; A/BT bf16, bias fp32, out = OutT.
// 256x256 tile, BK=64, 512 threads (8 waves: 2M x 4N), per-wave 128x64 out.
// LDS 128KB: A/B double-buffered, each buf 256x64 bf16, split in 128-row halves.
// Half-tile = 2 global_load_lds_dwordx4 per thread. Stage order per K-block T:
//   ph0: (T+1).Bhalf1 (other buf)   ph1: (T+2).Ahalf0
//   ph2: (T+2).Ahalf1               ph3: (T+2).Bhalf0
// All A frag ds_reads + bf01 in ph0, bf23 in ph1 -> every stage target's reads
// are complete one barrier earlier (race-free). vmcnt(6) once per K-tile
// (3 half-tiles in flight); vmcnt(0) only at T==NT-2. XOR chunk swizzle
// (gch = ch ^ (row&7)) keeps ds_read_b128 conflict-free (measured 0).
#define MQ(MH, NH)                                                                   \
  {                                                                                  \
    _Pragma("unroll") for (int mi = 0; mi < 4; ++mi)                                 \
        _Pragma("unroll") for (int nj = 0; nj < 2; ++nj) {                           \
      acc[(MH)*4 + mi][(NH)*2 + nj] = __builtin_amdgcn_mfma_f32_16x16x32_bf16(       \
          af[(MH)*4 + mi][0], bf[(NH)*2 + nj][0], acc[(MH)*4 + mi][(NH)*2 + nj],     \
          0, 0, 0);                                                                  \
      acc[(MH)*4 + mi][(NH)*2 + nj] = __builtin_amdgcn_mfma_f32_16x16x32_bf16(       \
          af[(MH)*4 + mi][1], bf[(NH)*2 + nj][1], acc[(MH)*4 + mi][(NH)*2 + nj],     \
          0, 0, 0);                                                                  \
    }                                                                                \
  }

#define AOFF(mi, k2) ((((wr << 7) + ((mi) << 4) + lm) << 6) + (((((k2) << 2) + lq) ^ sz) << 3))
#define BOFF(nj, k2) ((((wc << 6) + ((nj) << 4) + lm) << 6) + (((((k2) << 2) + lq) ^ sz) << 3))

template <typename OutT>
__global__ __launch_bounds__(512, 2) void gemm256_bt_bias(
    const u16* __restrict__ A, const u16* __restrict__ BT,
    const float* __restrict__ bias, OutT* __restrict__ C, int M, int N, int K) {
  __shared__ __align__(16) u16 As[2 * 16384];  // 64 KB
  __shared__ __align__(16) u16 Bs[2 * 16384];  // 64 KB
  const int mt = M >> 8;
  // T1: bijective XCD swizzle (grid % 8 == 0): XCD x owns one contiguous chunk
  // -> with bm-fastest order each XCD keeps a single B panel hot in its L2.
  const int cpx = gridDim.x >> 3;
  const int bid = blockIdx.x;
  const int wg = (bid & 7) * cpx + (bid >> 3);
  const int bm = wg % mt, bn = wg / mt;
  const int m0 = bm << 8, n0 = bn << 8;
  const int tid = threadIdx.x;
  const int lane = tid & 63, wid = tid >> 6;
  const int wr = wid >> 2, wc = wid & 3;    // wave tile: rows wr*128, cols wc*64
  const int lq = lane >> 4, lm = lane & 15;
  const int sz = lm & 7;
  const int NT = K >> 6;  // assumes K >= 128

  auto stage = [&](int h) {  // stage half-tile h (h = 4*tile + j)
    int t = h >> 2, j = h & 3;
    const u16* src;
    u16* dst;
    if (j < 2) { src = A + (size_t)(m0 + (j << 7)) * K; dst = As; }
    else       { src = BT + (size_t)(n0 + ((j & 1) << 7)) * K; dst = Bs; }
    dst += ((t & 1) << 14) + ((j & 1) << 13);
    const size_t kb = (size_t)(t << 6);
#pragma unroll
    for (int l = 0; l < 2; ++l) {
      int slot = (l << 9) + tid;          // 1024 chunks of 16B per half-tile
      int row = slot >> 3;
      int gch = (slot & 7) ^ (row & 7);   // LDS slot ch holds global chunk gch
      cp16(src + (size_t)row * K + kb + (gch << 3), (char*)dst + slot * 16);
    }
  };

  floatx4 acc[8][4];
#pragma unroll
  for (int i = 0; i < 8; ++i)
#pragma unroll
    for (int j = 0; j < 4; ++j) { acc[i][j].x = 0.f; acc[i][j].y = 0.f; acc[i][j].z = 0.f; acc[i][j].w = 0.f; }
  short8 af[8][2], bf[4][2];

  // prologue: tile0 fully + tile1 halves 0-2; wait tile0 landed (3 halves in flight)
#pragma unroll
  for (int h = 0; h < 7; ++h)
    if (h < 4 * NT) stage(h);
  asm volatile("s_waitcnt vmcnt(6)" ::: "memory");
  __builtin_amdgcn_s_barrier();

  for (int T = 0; T < NT; ++T) {
    const u16* Asb = As + ((T & 1) << 14);
    const u16* Bsb = Bs + ((T & 1) << 14);
    const int hb = (T << 2) + 7;
    // ---- phase 0: all A frags + bf01; stage (T+1).B1
#pragma unroll
    for (int mi = 0; mi < 8; ++mi) {
      af[mi][0] = *(const short8*)(Asb + AOFF(mi, 0));
      af[mi][1] = *(const short8*)(Asb + AOFF(mi, 1));
    }
#pragma unroll
    for (int nj = 0; nj < 2; ++nj) {
      bf[nj][0] = *(const short8*)(Bsb + BOFF(nj, 0));
      bf[nj][1] = *(const short8*)(Bsb + BOFF(nj, 1));
    }
    if (hb < 4 * NT) stage(hb);
    __builtin_amdgcn_s_barrier();
    asm volatile("s_waitcnt lgkmcnt(0)" ::: "memory");
    __builtin_amdgcn_sched_barrier(0);
    __builtin_amdgcn_s_setprio(1);
    MQ(0, 0);
    __builtin_amdgcn_s_setprio(0);
    __builtin_amdgcn_s_barrier();
    // ---- phase 1: bf23; stage (T+2).A0
#pragma unroll
    for (int nj = 2; nj < 4; ++nj) {
      bf[nj][0] = *(const short8*)(Bsb + BOFF(nj, 0));
      bf[nj][1] = *(const short8*)(Bsb + BOFF(nj, 1));
    }
    if (hb + 1 < 4 * NT) stage(hb + 1);
    __builtin_amdgcn_s_barrier();
    asm volatile("s_waitcnt lgkmcnt(0)" ::: "memory");
    __builtin_amdgcn_sched_barrier(0);
    __builtin_amdgcn_s_setprio(1);
    MQ(0, 1);
    __builtin_amdgcn_s_setprio(0);
    __builtin_amdgcn_s_barrier();
    // ---- phase 2: stage (T+2).A1
    if (hb + 2 < 4 * NT) stage(hb + 2);
    __builtin_amdgcn_s_barrier();
    __builtin_amdgcn_s_setprio(1);
    MQ(1, 0);
    __builtin_amdgcn_s_setprio(0);
    __builtin_amdgcn_s_barrier();
    // ---- phase 3: stage (T+2).B0; MFMA; counted vmcnt; barrier
    if (hb + 3 < 4 * NT) stage(hb + 3);
    __builtin_amdgcn_s_barrier();
    __builtin_amdgcn_s_setprio(1);
    MQ(1, 1);
    __builtin_amdgcn_s_setprio(0);
    if (T == NT - 2) { asm volatile("s_waitcnt vmcnt(0)" ::: "memory"); }
    else if (T < NT - 2) { asm volatile("s_waitcnt vmcnt(6)" ::: "memory"); }
    __builtin_amdgcn_s_barrier();
  }

  // Epilogue: stage C through LDS (4 slabs of 64 rows x 256 cols f32 = 64KB in As)
  // so global writes are full coalesced rows (fixes partial-line RMW inflation).
  float bv[4];
#pragma unroll
  for (int nj = 0; nj < 4; ++nj) bv[nj] = bias[n0 + (wc << 6) + nj * 16 + lm];
  float* Cs = (float*)As;
#pragma unroll
  for (int s = 0; s < 4; ++s) {
    __syncthreads();
    if (wr == (s >> 1)) {
#pragma unroll
      for (int mi2 = 0; mi2 < 4; ++mi2) {
        const int mi = ((s & 1) << 2) + mi2;
#pragma unroll
        for (int nj = 0; nj < 4; ++nj)
#pragma unroll
          for (int rr = 0; rr < 4; ++rr)
            Cs[(mi2 * 16 + lq * 4 + rr) * 256 + (wc << 6) + nj * 16 + lm] =
                acc[mi][nj][rr] + bv[nj];
      }
    }
    __syncthreads();
#pragma unroll
    for (int w = 0; w < 8; ++w) {
      int fi = (w << 9) + tid;  // 4096 float4 chunks; each wave writes one row
      int rl = fi >> 6, cc = fi & 63;
      float4 v = *(const float4*)&Cs[rl * 256 + (cc << 2)];
      size_t grow = (size_t)(m0 + (s << 6) + rl) * N + n0 + (cc << 2);
      if constexpr (sizeof(OutT) == 2) {
        union { u16 u[4]; u64 q; } o;
        o.u[0] = f2bf(v.x); o.u[1] = f2bf(v.y); o.u[2] = f2bf(v.z); o.u[3] = f2bf(v.w);
        *(u64*)((u16*)C + grow) = o.q;
      } else {
        *(float4*)((float*)C + grow) = v;
      }
    }
  }
}

// ---------------------------------------------------------------- gates + elementwise
// Per (m-tile of 128 rows, blk of 8): MFMA tile M=128, N=256 (gx rows 0..127 of
// WGT^T, ga rows 128..255), K=256. Wave layout pairs gx/ga for the same output
// element in the SAME lane. Epilogue fully in-register.
__global__ __launch_bounds__(256, 2) void gate_elem_kernel(
    const u16* __restrict__ xh, const u16* __restrict__ wgt,
    const float* __restrict__ bgx, const float* __restrict__ bga,
    const float* __restrict__ arp,
    float* __restrict__ ga_out, u16* __restrict__ xr_out, u16* __restrict__ xi_out) {
  __shared__ __align__(16) u16 As[128 * 64];  // 16 KB
  __shared__ __align__(16) u16 Bs[256 * 64];  // 32 KB

  const int m0 = blockIdx.x << 7;
  const int blk = blockIdx.y;
  const int tid = threadIdx.x;
  const int lane = tid & 63, wid = tid >> 6;
  const int wm = (wid & 1) << 6, wn = (wid >> 1) << 6;
  const int lq = lane >> 4, lm = lane & 15;

  floatx4 acc[4][8];
#pragma unroll
  for (int i = 0; i < 4; ++i)
#pragma unroll
    for (int j = 0; j < 8; ++j) { acc[i][j].x = 0.f; acc[i][j].y = 0.f; acc[i][j].z = 0.f; acc[i][j].w = 0.f; }

  const u16* Ag = xh + (size_t)m0 * 2048 + blk * 256;  // row stride 2048
  const u16* Bg = wgt + (size_t)blk * 65536;           // [256][256] row-major

  for (int kt = 0; kt < 256; kt += 64) {
#pragma unroll
    for (int j = 0; j < 4; ++j) {
      int slot = (j << 8) + tid;
      int row = slot >> 3, ch = slot & 7;
      int gch = ch ^ (row & 7);
      cp16(Ag + (size_t)row * 2048 + kt + (gch << 3), (char*)As + slot * 16);
    }
#pragma unroll
    for (int j = 0; j < 8; ++j) {
      int slot = (j << 8) + tid;
      int row = slot >> 3, ch = slot & 7;
      int gch = ch ^ (row & 7);
      cp16(Bg + (size_t)row * 256 + kt + (gch << 3), (char*)Bs + slot * 16);
    }
    WAIT_VM();
    __syncthreads();
#pragma unroll
    for (int kk = 0; kk < 64; kk += 32) {
      const int lc = (kk >> 3) + lq;
      short8 af[4], bfr[8];
#pragma unroll
      for (int mi = 0; mi < 4; ++mi) {
        int r = wm + mi * 16 + lm;
        af[mi] = *(const short8*)&As[r * 64 + ((lc ^ (r & 7)) << 3)];
      }
#pragma unroll
      for (int ni = 0; ni < 8; ++ni) {
        int r = (ni < 4) ? (wn + ni * 16 + lm) : (128 + wn + (ni - 4) * 16 + lm);
        bfr[ni] = *(const short8*)&Bs[r * 64 + ((lc ^ (r & 7)) << 3)];
      }
#pragma unroll
      for (int mi = 0; mi < 4; ++mi)
#pragma unroll
        for (int ni = 0; ni < 8; ++ni)
          acc[mi][ni] = __builtin_amdgcn_mfma_f32_16x16x32_bf16(af[mi], bfr[ni], acc[mi][ni], 0, 0, 0);
    }
    __syncthreads();
  }

#pragma unroll
  for (int ni = 0; ni < 4; ++ni) {
    const int c = (blk << 7) + wn + ni * 16 + lm;
    const float bxv = bgx[c], bav = bga[c];
    const float sp = log1pf(__expf(arp[c]));  // softplus(a_real_param)
#pragma unroll
    for (int mi = 0; mi < 4; ++mi) {
      const size_t rowg0 = (size_t)m0 + wm + mi * 16 + lq * 4;
#pragma unroll
      for (int r = 0; r < 4; ++r) {
        const size_t rowg = rowg0 + r;
        float gxv = sigmoidf_(acc[mi][ni][r] + bxv);
        float gav = sigmoidf_(acc[mi][ni + 4][r] + bav);
        float mag = __expf(-8.f * gav * sp);
        float norm = sqrtf(fmaxf(1.f - mag * mag, 0.f));
        float f = norm * gxv;
        ga_out[rowg * 1024 + c] = gav;  // fp32: scan precision requires it
        xr_out[rowg * 1024 + c] = f2bf(f * bf2f(xh[rowg * 2048 + c]));
        xi_out[rowg * 1024 + c] = f2bf(f * bf2f(xh[rowg * 2048 + 1024 + c]));
      }
    }
  }
}

// ---------------------------------------------------------------- scan (chunk=64, 64 chunks)
__global__ __launch_bounds__(256) void scan_pass1(
    const float* __restrict__ ga, const u16* __restrict__ xr, const u16* __restrict__ xi,
    const float* __restrict__ arp, const float* __restrict__ aip,
    float* __restrict__ Ar, float* __restrict__ Ai,
    float* __restrict__ Xr, float* __restrict__ Xi) {
  int tid = blockIdx.x * 256 + threadIdx.x;  // [0, 4*64*1024)
  int c = tid & 1023;
  int chunk = (tid >> 10) & 63;
  int b = tid >> 16;
  float sp = log1pf(__expf(arp[c]));
  float aim = aip[c];
  size_t base = ((size_t)b * 4096 + chunk * 64) * 1024 + c;
  float Arr = 1.f, Aii = 0.f, Xrr = 0.f, Xii = 0.f;
#pragma unroll 4
  for (int i = 0; i < 64; ++i) {
    size_t idx = base + (size_t)i * 1024;
    float g = ga[idx];
    float mag = __expf(-8.f * g * sp);
    float s, co;
    __sincosf(aim * g, &s, &co);
    float ar = mag * co, ai = mag * s;
    float nxr = ar * Xrr - ai * Xii + bf2f(xr[idx]);
    float nxi = ar * Xii + ai * Xrr + bf2f(xi[idx]);
    Xrr = nxr; Xii = nxi;
    float nar = ar * Arr - ai * Aii;
    float nai = ar * Aii + ai * Arr;
    Arr = nar; Aii = nai;
  }
  Ar[tid] = Arr; Ai[tid] = Aii; Xr[tid] = Xrr; Xi[tid] = Xii;
}

__global__ __launch_bounds__(256) void scan_pass2(
    const float* __restrict__ Ar, const float* __restrict__ Ai,
    const float* __restrict__ Xr, const float* __restrict__ Xi,
    float* __restrict__ Hr, float* __restrict__ Hi) {
  int tid = blockIdx.x * 256 + threadIdx.x;  // [0, 4096)
  int c = tid & 1023, b = tid >> 10;
  float hr = 0.f, hi = 0.f;
  for (int j = 0; j < 64; ++j) {
    int idx = (b << 16) + (j << 10) + c;
    Hr[idx] = hr; Hi[idx] = hi;
    float ar = Ar[idx], ai = Ai[idx];
    float nhr = ar * hr - ai * hi + Xr[idx];
    float nhi = ar * hi + ai * hr + Xi[idx];
    hr = nhr; hi = nhi;
  }
}

__global__ __launch_bounds__(256) void scan_pass3(
    const float* __restrict__ ga, const u16* __restrict__ xr, const u16* __restrict__ xi,
    const float* __restrict__ arp, const float* __restrict__ aip,
    const float* __restrict__ Hr, const float* __restrict__ Hi,
    u16* __restrict__ h_out, float* __restrict__ tail) {
  int tid = blockIdx.x * 256 + threadIdx.x;
  int c = tid & 1023;
  int chunk = (tid >> 10) & 63;
  int b = tid >> 16;
  float sp = log1pf(__expf(arp[c]));
  float aim = aip[c];
  size_t row0 = (size_t)b * 4096 + chunk * 64;
  size_t base = row0 * 1024 + c;
  float hr = Hr[tid], hi = Hi[tid];
#pragma unroll 4
  for (int i = 0; i < 64; ++i) {
    size_t idx = base + (size_t)i * 1024;
    float g = ga[idx];
    float mag = __expf(-8.f * g * sp);
    float s, co;
    __sincosf(aim * g, &s, &co);
    float ar = mag * co, ai = mag * s;
    float nhr = ar * hr - ai * hi + bf2f(xr[idx]);
    float nhi = ar * hi + ai * hr + bf2f(xi[idx]);
    hr = nhr; hi = nhi;
    size_t r = row0 + i;
    h_out[r * 2048 + c] = f2bf(hr);
    h_out[r * 2048 + 1024 + c] = f2bf(hi);
  }
  if (chunk == 63) {  // s = 4095
    tail[(size_t)b * 2048 + c] = hr;
    tail[(size_t)b * 2048 + 1024 + c] = hi;
  }
}

// ---------------------------------------------------------------- launch
static const size_t OFF_XH = 0;            // u16 [16384][2048] (later: h)
static const size_t OFF_GA = 67108864;     // f32 [16384][1024]  (first: XB u16 [16384][2048])
static const size_t OFF_XR = 134217728;    // u16 [16384][1024]
static const size_t OFF_XI = 167772160;    // u16 [16384][1024]
static const size_t OFF_WIT = 201326592;   // u16 [2048][2048]  W_in^T
static const size_t OFF_WOT = 209715200;   // u16 [2048][2048]  W_out^T
static const size_t OFF_WGT = 218103808;   // u16 [8][256][256] gate weights^T (gx|ga)
static const size_t OFF_AGR = 219152384;   // f32 [262144] chunk aggregates
static const size_t OFF_AGI = 220200960;
static const size_t OFF_AXR = 221249536;
static const size_t OFF_AXI = 222298112;
static const size_t OFF_HPR = 223346688;   // f32 [262144] chunk prefixes
static const size_t OFF_HPI = 224395264;

extern "C" void kernel_launch(void* const* d_in, const int* in_sizes, int n_in,
                              void* d_out, int out_size, void* d_ws, size_t ws_size,
                              hipStream_t stream) {
  const float* x    = (const float*)d_in[0];
  const float* arp  = (const float*)d_in[1];
  const float* aip  = (const float*)d_in[2];
  const float* W_in = (const float*)d_in[3];
  const float* b_in = (const float*)d_in[4];
  const float* Wg_x = (const float*)d_in[5];
  const float* bg_x = (const float*)d_in[6];
  const float* Wg_a = (const float*)d_in[7];
  const float* bg_a = (const float*)d_in[8];
  const float* W_out = (const float*)d_in[9];
  const float* b_out = (const float*)d_in[10];

  char* ws = (char*)d_ws;
  u16* XH = (u16*)(ws + OFF_XH);
  u16* XB = (u16*)(ws + OFF_GA);   // bf16 copy of x; dead once GEMM1 finishes
  float* GA = (float*)(ws + OFF_GA);
  u16* XR = (u16*)(ws + OFF_XR);
  u16* XI = (u16*)(ws + OFF_XI);
  u16* WIT = (u16*)(ws + OFF_WIT);
  u16* WOT = (u16*)(ws + OFF_WOT);
  u16* WGT = (u16*)(ws + OFF_WGT);
  float* AGR = (float*)(ws + OFF_AGR);
  float* AGI = (float*)(ws + OFF_AGI);
  float* AXR = (float*)(ws + OFF_AXR);
  float* AXI = (float*)(ws + OFF_AXI);
  float* HPR = (float*)(ws + OFF_HPR);
  float* HPI = (float*)(ws + OFF_HPI);

  float* y_out = (float*)d_out;
  float* h_last = (float*)d_out + (size_t)16384 * 2048;

  // x -> bf16
  convert_f32_bf16<<<16384, 256, 0, stream>>>(x, XB, (long)16384 * 2048);

  dim3 tb(32, 8);
  transpose_f32_bf16<<<dim3(64, 64, 1), tb, 0, stream>>>(W_in, WIT, 2048, 2048, 0, 0);
  transpose_f32_bf16<<<dim3(64, 64, 1), tb, 0, stream>>>(W_out, WOT, 2048, 2048, 0, 0);
  transpose_f32_bf16<<<dim3(4, 8, 8), tb, 0, stream>>>(Wg_x, WGT, 256, 128, 32768, 65536);
  transpose_f32_bf16<<<dim3(4, 8, 8), tb, 0, stream>>>(Wg_a, WGT + 32768, 256, 128, 32768, 65536);

  // x_h = x @ W_in + b_in  (bf16 out); 64x8 tiles of 256^2
  gemm256_bt_bias<u16><<<512, 512, 0, stream>>>(XB, WIT, b_in, XH, 16384, 2048, 2048);
  // gates + a/x scan inputs (overwrites XB region with GA)
  gate_elem_kernel<<<dim3(128, 8), 256, 0, stream>>>(XH, WGT, bg_x, bg_a, arp, GA, XR, XI);
  // chunked complex scan
  scan_pass1<<<1024, 256, 0, stream>>>(GA, XR, XI, arp, aip, AGR, AGI, AXR, AXI);
  scan_pass2<<<16, 256, 0, stream>>>(AGR, AGI, AXR, AXI, HPR, HPI);
  scan_pass3<<<1024, 256, 0, stream>>>(GA, XR, XI, arp, aip, HPR, HPI, XH /*h aliases x_h*/, h_last);
  // y = h @ W_out + b_out  (fp32 out)
  gemm256_bt_bias<float><<<512, 512, 0, stream>>>(XH, WOT, b_out, y_out, 16384, 2048, 2048);
}

// Round 2
// 711.373 us; speedup vs baseline: 1.1698x; 1.0277x over previous
//
#include <hip/hip_runtime.h>
#include <hip/hip_bf16.h>

// RG-LRU forward, MI355X/gfx950.
// I/O dtype: fp32. Internally bf16 MFMA GEMMs, fp32 gate_a + fp32 scan state.
// R4: 256^2 GEMM K-loop rescheduled — ds_reads balanced 4/8/8/4 across phases,
// issued INSIDE the MFMA regions one phase ahead of use (drained by the next
// phase's lgkmcnt(0)), counted vmcnt(8)/vmcnt(4) before barriers. Epilogue
// Cs stride 260 kills the 4-way ds_write conflict.

typedef unsigned short u16;
typedef unsigned int u32;
typedef unsigned long long u64;
typedef __attribute__((ext_vector_type(8))) short short8;
typedef __attribute__((ext_vector_type(4))) float floatx4;

#define DEV __device__ __forceinline__

DEV float bf2f(u16 u) { union { u32 i; float f; } v; v.i = ((u32)u) << 16; return v.f; }
DEV u16 f2bf(float f) {
  union { float f; u32 i; } v; v.f = f;
  u32 r = v.i + 0x7fffu + ((v.i >> 16) & 1u);  // RNE
  return (u16)(r >> 16);
}
DEV float sigmoidf_(float x) { return 1.f / (1.f + __expf(-x)); }

#if __has_builtin(__builtin_amdgcn_global_load_lds)
#define USE_ASYNC_LDS 1
#endif

DEV void cp16(const void* g, void* l) {
#if defined(USE_ASYNC_LDS) && defined(__HIP_DEVICE_COMPILE__)
  __builtin_amdgcn_global_load_lds((const __attribute__((address_space(1))) u32*)g,
                                   (__attribute__((address_space(3))) u32*)l, 16, 0, 0);
#else
  *(short8*)l = *(const short8*)g;
#endif
}
#define WAIT_VM() asm volatile("s_waitcnt vmcnt(0)" ::: "memory")
#define LGKM0()  do { asm volatile("s_waitcnt lgkmcnt(0)" ::: "memory"); __builtin_amdgcn_sched_barrier(0); } while (0)

// ---------------------------------------------------------------- convert fp32 -> bf16
__global__ __launch_bounds__(256) void convert_f32_bf16(
    const float* __restrict__ src, u16* __restrict__ dst, long n) {
  long i = ((long)blockIdx.x * 256 + threadIdx.x) * 8;
  if (i >= n) return;
  float4 a = *(const float4*)(src + i);
  float4 b = *(const float4*)(src + i + 4);
  union { u16 u[8]; short8 v; } o;
  o.u[0] = f2bf(a.x); o.u[1] = f2bf(a.y); o.u[2] = f2bf(a.z); o.u[3] = f2bf(a.w);
  o.u[4] = f2bf(b.x); o.u[5] = f2bf(b.y); o.u[6] = f2bf(b.z); o.u[7] = f2bf(b.w);
  *(short8*)(dst + i) = o.v;
}

// ---------------------------------------------------------------- transpose + convert
__global__ __launch_bounds__(256) void transpose_f32_bf16(
    const float* __restrict__ src, u16* __restrict__ dst, int R, int C,
    long sBatch, long dBatch) {
  __shared__ u16 tile[32][33];
  const int n = blockIdx.z;
  src += (long)n * sBatch;
  dst += (long)n * dBatch;
  const int c0 = blockIdx.x * 32, r0 = blockIdx.y * 32;
  const int tx = threadIdx.x, ty = threadIdx.y;  // (32,8)
#pragma unroll
  for (int i = 0; i < 32; i += 8)
    tile[ty + i][tx] = f2bf(src[(long)(r0 + ty + i) * C + c0 + tx]);
  __syncthreads();
#pragma unroll
  for (int i = 0; i < 32; i += 8) dst[(long)(c0 + ty + i) * R + r0 + tx] = tile[tx][ty + i];
}

// ---------------------------------------------------------------- 256^2 8-phase GEMM
// Per K-tile T (BK=64), phases p0..p3 each: [gap: stage 1 half-tile][barrier]
// [lgkmcnt(0)][reads for NEXT phase, interleaved with 16 MFMA][vmcnt][barrier].
// Quadrants: p0=MQ(0,0) p1=MQ(0,1) p2=MQ(1,0) p3=MQ(1,1).
// Reads: p0: bf23(T); p1: af4-7(T); p2: af0-3(T+1); p3: bf01(T+1).
// Stages: g0=(T+1).B1  g1=(T+2).A0  g2=(T+2).B0  g3=(T+2).A1.
// vmcnt(8) end-p1 -> (T+1).A0 landed (collective via following barrier);
// vmcnt(4) end-p2 -> (T+1).B0/A1/B1 landed. Never 0 until T>=NT-2.
#define MQ(MH, NH)                                                                   \
  {                                                                                  \
    _Pragma("unroll") for (int mi = 0; mi < 4; ++mi)                                 \
        _Pragma("unroll") for (int nj = 0; nj < 2; ++nj) {                           \
      acc[(MH)*4 + mi][(NH)*2 + nj] = __builtin_amdgcn_mfma_f32_16x16x32_bf16(       \
          af[(MH)*4 + mi][0], bf[(NH)*2 + nj][0], acc[(MH)*4 + mi][(NH)*2 + nj],     \
          0, 0, 0);                                                                  \
      acc[(MH)*4 + mi][(NH)*2 + nj] = __builtin_amdgcn_mfma_f32_16x16x32_bf16(       \
          af[(MH)*4 + mi][1], bf[(NH)*2 + nj][1], acc[(MH)*4 + mi][(NH)*2 + nj],     \
          0, 0, 0);                                                                  \
    }                                                                                \
  }

#define AOFF(mi, k2) ((((wr << 7) + ((mi) << 4) + lm) << 6) + (((((k2) << 2) + lq) ^ sz) << 3))
#define BOFF(nj, k2) ((((wc << 6) + ((nj) << 4) + lm) << 6) + (((((k2) << 2) + lq) ^ sz) << 3))

// read A fragments mi in [m0_, m0_+4) from buffer p
#define RD_A4(m0_, p)                                                   \
  {                                                                     \
    _Pragma("unroll") for (int mi = (m0_); mi < (m0_) + 4; ++mi) {      \
      af[mi][0] = *(const short8*)((p) + AOFF(mi, 0));                  \
      af[mi][1] = *(const short8*)((p) + AOFF(mi, 1));                  \
    }                                                                   \
  }
// read B fragments nj in [n0_, n0_+2) from buffer p
#define RD_B2(n0_, p)                                                   \
  {                                                                     \
    _Pragma("unroll") for (int nj = (n0_); nj < (n0_) + 2; ++nj) {      \
      bf[nj][0] = *(const short8*)((p) + BOFF(nj, 0));                  \
      bf[nj][1] = *(const short8*)((p) + BOFF(nj, 1));                  \
    }                                                                   \
  }

template <typename OutT>
__global__ __launch_bounds__(512, 2) void gemm256_bt_bias(
    const u16* __restrict__ A, const u16* __restrict__ BT,
    const float* __restrict__ bias, OutT* __restrict__ C, int M, int N, int K) {
  __shared__ __align__(16) u16 SM[65536];  // 128 KB: As | Bs (Cs spans both in epilogue)
  u16* As = SM;
  u16* Bs = SM + 32768;
  const int mt = M >> 8;
  // T1: bijective XCD swizzle (grid % 8 == 0); bm-fastest so each XCD reuses one B panel.
  const int cpx = gridDim.x >> 3;
  const int bid = blockIdx.x;
  const int wg = (bid & 7) * cpx + (bid >> 3);
  const int bm = wg % mt, bn = wg / mt;
  const int m0 = bm << 8, n0 = bn << 8;
  const int tid = threadIdx.x;
  const int lane = tid & 63, wid = tid >> 6;
  const int wr = wid >> 2, wc = wid & 3;  // wave tile: rows wr*128, cols wc*64
  const int lq = lane >> 4, lm = lane & 15;
  const int sz = lm & 7;
  const int NT = K >> 6;  // assumes NT >= 3

  // stage half-tile j (0=A0,1=A1,2=B0,3=B1) of K-tile t into buffer t&1
  auto stageH = [&](int t, int j) {
    const u16* src;
    u16* dst;
    if (j < 2) { src = A + (size_t)(m0 + (j << 7)) * K; dst = As; }
    else       { src = BT + (size_t)(n0 + ((j & 1) << 7)) * K; dst = Bs; }
    dst += ((t & 1) << 14) + ((j & 1) << 13);
    const size_t kb = (size_t)(t << 6);
#pragma unroll
    for (int l = 0; l < 2; ++l) {
      int slot = (l << 9) + tid;          // 1024 chunks of 16B per half-tile
      int row = slot >> 3;
      int gch = (slot & 7) ^ (row & 7);   // LDS slot ch holds global chunk gch
      cp16(src + (size_t)row * K + kb + (gch << 3), (char*)dst + slot * 16);
    }
  };

  floatx4 acc[8][4];
#pragma unroll
  for (int i = 0; i < 8; ++i)
#pragma unroll
    for (int j = 0; j < 4; ++j) { acc[i][j].x = 0.f; acc[i][j].y = 0.f; acc[i][j].z = 0.f; acc[i][j].w = 0.f; }
  short8 af[8][2], bf[4][2];

  // prologue: tile0 {A0,B0,A1,B1} + tile1 {A0,B0,A1}; drain tile0 (8 loads) -> vmcnt(6)
  stageH(0, 0); stageH(0, 2); stageH(0, 1); stageH(0, 3);
  stageH(1, 0); stageH(1, 2); stageH(1, 1);
  asm volatile("s_waitcnt vmcnt(6)" ::: "memory");
  __builtin_amdgcn_s_barrier();
  RD_A4(0, As);   // af0-3 (tile0)
  RD_B2(0, Bs);   // bf01 (tile0)

  for (int T = 0; T < NT; ++T) {
    const u16* ca = As + ((T & 1) << 14);
    const u16* cb = Bs + ((T & 1) << 14);
    const u16* na = As + (((T + 1) & 1) << 14);
    const u16* nb = Bs + (((T + 1) & 1) << 14);
    const bool haveN1 = (T + 1 < NT), haveN2 = (T + 2 < NT);
    // ---- phase 0: MQ(0,0) || read bf23(T); stage (T+1).B1
    if (haveN1) stageH(T + 1, 3);
    __builtin_amdgcn_s_barrier();
    LGKM0();
    RD_B2(2, cb);
    __builtin_amdgcn_s_setprio(1);
    MQ(0, 0);
    __builtin_amdgcn_s_setprio(0);
    __builtin_amdgcn_s_barrier();
    // ---- phase 1: MQ(0,1) || read af4-7(T); stage (T+2).A0; vmcnt(8)
    if (haveN2) stageH(T + 2, 0);
    __builtin_amdgcn_s_barrier();
    LGKM0();
    RD_A4(4, ca);
    __builtin_amdgcn_s_setprio(1);
    MQ(0, 1);
    __builtin_amdgcn_s_setprio(0);
    if (T < NT - 2) { asm volatile("s_waitcnt vmcnt(8)" ::: "memory"); }
    else            { asm volatile("s_waitcnt vmcnt(0)" ::: "memory"); }
    __builtin_amdgcn_s_barrier();
    // ---- phase 2: MQ(1,0) || read af0-3(T+1); stage (T+2).B0; vmcnt(4)
    if (haveN2) stageH(T + 2, 2);
    __builtin_amdgcn_s_barrier();
    LGKM0();
    if (haveN1) RD_A4(0, na);
    __builtin_amdgcn_s_setprio(1);
    MQ(1, 0);
    __builtin_amdgcn_s_setprio(0);
    if (T < NT - 2) { asm volatile("s_waitcnt vmcnt(4)" ::: "memory"); }
    else            { asm volatile("s_waitcnt vmcnt(0)" ::: "memory"); }
    __builtin_amdgcn_s_barrier();
    // ---- phase 3: MQ(1,1) || read bf01(T+1); stage (T+2).A1
    if (haveN2) stageH(T + 2, 1);
    __builtin_amdgcn_s_barrier();
    LGKM0();
    if (haveN1) RD_B2(0, nb);
    __builtin_amdgcn_s_setprio(1);
    MQ(1, 1);
    __builtin_amdgcn_s_setprio(0);
    __builtin_amdgcn_s_barrier();
  }

  // Epilogue: stage C through LDS (4 slabs of 64 rows x 256 cols, stride 260 f32)
  // -> full coalesced row writes; stride 260 (row-diff-4 offset = 16 banks) keeps
  // the ds_write pattern at 2-way (free).
  float bv[4];
#pragma unroll
  for (int nj = 0; nj < 4; ++nj) bv[nj] = bias[n0 + (wc << 6) + nj * 16 + lm];
  float* Cs = (float*)SM;  // 64*260*4 = 66560 B of the 128 KB
#pragma unroll
  for (int s = 0; s < 4; ++s) {
    __syncthreads();
    if (wr == (s >> 1)) {
#pragma unroll
      for (int mi2 = 0; mi2 < 4; ++mi2) {
        const int mi = ((s & 1) << 2) + mi2;
#pragma unroll
        for (int nj = 0; nj < 4; ++nj)
#pragma unroll
          for (int rr = 0; rr < 4; ++rr)
            Cs[(mi2 * 16 + lq * 4 + rr) * 260 + (wc << 6) + nj * 16 + lm] =
                acc[mi][nj][rr] + bv[nj];
      }
    }
    __syncthreads();
#pragma unroll
    for (int w = 0; w < 8; ++w) {
      int fi = (w << 9) + tid;  // 4096 float4 chunks; each wave writes one row
      int rl = fi >> 6, cc = fi & 63;
      float4 v = *(const float4*)&Cs[rl * 260 + (cc << 2)];
      size_t grow = (size_t)(m0 + (s << 6) + rl) * N + n0 + (cc << 2);
      if constexpr (sizeof(OutT) == 2) {
        union { u16 u[4]; u64 q; } o;
        o.u[0] = f2bf(v.x); o.u[1] = f2bf(v.y); o.u[2] = f2bf(v.z); o.u[3] = f2bf(v.w);
        *(u64*)((u16*)C + grow) = o.q;
      } else {
        *(float4*)((float*)C + grow) = v;
      }
    }
  }
}

// ---------------------------------------------------------------- gates + elementwise
__global__ __launch_bounds__(256, 2) void gate_elem_kernel(
    const u16* __restrict__ xh, const u16* __restrict__ wgt,
    const float* __restrict__ bgx, const float* __restrict__ bga,
    const float* __restrict__ arp,
    float* __restrict__ ga_out, u16* __restrict__ xr_out, u16* __restrict__ xi_out) {
  __shared__ __align__(16) u16 As[128 * 64];  // 16 KB
  __shared__ __align__(16) u16 Bs[256 * 64];  // 32 KB

  const int m0 = blockIdx.x << 7;
  const int blk = blockIdx.y;
  const int tid = threadIdx.x;
  const int lane = tid & 63, wid = tid >> 6;
  const int wm = (wid & 1) << 6, wn = (wid >> 1) << 6;
  const int lq = lane >> 4, lm = lane & 15;

  floatx4 acc[4][8];
#pragma unroll
  for (int i = 0; i < 4; ++i)
#pragma unroll
    for (int j = 0; j < 8; ++j) { acc[i][j].x = 0.f; acc[i][j].y = 0.f; acc[i][j].z = 0.f; acc[i][j].w = 0.f; }

  const u16* Ag = xh + (size_t)m0 * 2048 + blk * 256;  // row stride 2048
  const u16* Bg = wgt + (size_t)blk * 65536;           // [256][256] row-major

  for (int kt = 0; kt < 256; kt += 64) {
#pragma unroll
    for (int j = 0; j < 4; ++j) {
      int slot = (j << 8) + tid;
      int row = slot >> 3, ch = slot & 7;
      int gch = ch ^ (row & 7);
      cp16(Ag + (size_t)row * 2048 + kt + (gch << 3), (char*)As + slot * 16);
    }
#pragma unroll
    for (int j = 0; j < 8; ++j) {
      int slot = (j << 8) + tid;
      int row = slot >> 3, ch = slot & 7;
      int gch = ch ^ (row & 7);
      cp16(Bg + (size_t)row * 256 + kt + (gch << 3), (char*)Bs + slot * 16);
    }
    WAIT_VM();
    __syncthreads();
#pragma unroll
    for (int kk = 0; kk < 64; kk += 32) {
      const int lc = (kk >> 3) + lq;
      short8 af[4], bfr[8];
#pragma unroll
      for (int mi = 0; mi < 4; ++mi) {
        int r = wm + mi * 16 + lm;
        af[mi] = *(const short8*)&As[r * 64 + ((lc ^ (r & 7)) << 3)];
      }
#pragma unroll
      for (int ni = 0; ni < 8; ++ni) {
        int r = (ni < 4) ? (wn + ni * 16 + lm) : (128 + wn + (ni - 4) * 16 + lm);
        bfr[ni] = *(const short8*)&Bs[r * 64 + ((lc ^ (r & 7)) << 3)];
      }
#pragma unroll
      for (int mi = 0; mi < 4; ++mi)
#pragma unroll
        for (int ni = 0; ni < 8; ++ni)
          acc[mi][ni] = __builtin_amdgcn_mfma_f32_16x16x32_bf16(af[mi], bfr[ni], acc[mi][ni], 0, 0, 0);
    }
    __syncthreads();
  }

#pragma unroll
  for (int ni = 0; ni < 4; ++ni) {
    const int c = (blk << 7) + wn + ni * 16 + lm;
    const float bxv = bgx[c], bav = bga[c];
    const float sp = log1pf(__expf(arp[c]));  // softplus(a_real_param)
#pragma unroll
    for (int mi = 0; mi < 4; ++mi) {
      const size_t rowg0 = (size_t)m0 + wm + mi * 16 + lq * 4;
#pragma unroll
      for (int r = 0; r < 4; ++r) {
        const size_t rowg = rowg0 + r;
        float gxv = sigmoidf_(acc[mi][ni][r] + bxv);
        float gav = sigmoidf_(acc[mi][ni + 4][r] + bav);
        float mag = __expf(-8.f * gav * sp);
        float norm = sqrtf(fmaxf(1.f - mag * mag, 0.f));
        float f = norm * gxv;
        ga_out[rowg * 1024 + c] = gav;  // fp32: scan precision requires it
        xr_out[rowg * 1024 + c] = f2bf(f * bf2f(xh[rowg * 2048 + c]));
        xi_out[rowg * 1024 + c] = f2bf(f * bf2f(xh[rowg * 2048 + 1024 + c]));
      }
    }
  }
}

// ---------------------------------------------------------------- scan (chunk=64, 64 chunks)
__global__ __launch_bounds__(256) void scan_pass1(
    const float* __restrict__ ga, const u16* __restrict__ xr, const u16* __restrict__ xi,
    const float* __restrict__ arp, const float* __restrict__ aip,
    float* __restrict__ Ar, float* __restrict__ Ai,
    float* __restrict__ Xr, float* __restrict__ Xi) {
  int tid = blockIdx.x * 256 + threadIdx.x;  // [0, 4*64*1024)
  int c = tid & 1023;
  int chunk = (tid >> 10) & 63;
  int b = tid >> 16;
  float sp = log1pf(__expf(arp[c]));
  float aim = aip[c];
  size_t base = ((size_t)b * 4096 + chunk * 64) * 1024 + c;
  float Arr = 1.f, Aii = 0.f, Xrr = 0.f, Xii = 0.f;
#pragma unroll 4
  for (int i = 0; i < 64; ++i) {
    size_t idx = base + (size_t)i * 1024;
    float g = ga[idx];
    float mag = __expf(-8.f * g * sp);
    float s, co;
    __sincosf(aim * g, &s, &co);
    float ar = mag * co, ai = mag * s;
    float nxr = ar * Xrr - ai * Xii + bf2f(xr[idx]);
    float nxi = ar * Xii + ai * Xrr + bf2f(xi[idx]);
    Xrr = nxr; Xii = nxi;
    float nar = ar * Arr - ai * Aii;
    float nai = ar * Aii + ai * Arr;
    Arr = nar; Aii = nai;
  }
  Ar[tid] = Arr; Ai[tid] = Aii; Xr[tid] = Xrr; Xi[tid] = Xii;
}

__global__ __launch_bounds__(256) void scan_pass2(
    const float* __restrict__ Ar, const float* __restrict__ Ai,
    const float* __restrict__ Xr, const float* __restrict__ Xi,
    float* __restrict__ Hr, float* __restrict__ Hi) {
  int tid = blockIdx.x * 256 + threadIdx.x;  // [0, 4096)
  int c = tid & 1023, b = tid >> 10;
  float hr = 0.f, hi = 0.f;
  for (int j = 0; j < 64; ++j) {
    int idx = (b << 16) + (j << 10) + c;
    Hr[idx] = hr; Hi[idx] = hi;
    float ar = Ar[idx], ai = Ai[idx];
    float nhr = ar * hr - ai * hi + Xr[idx];
    float nhi = ar * hi + ai * hr + Xi[idx];
    hr = nhr; hi = nhi;
  }
}

__global__ __launch_bounds__(256) void scan_pass3(
    const float* __restrict__ ga, const u16* __restrict__ xr, const u16* __restrict__ xi,
    const float* __restrict__ arp, const float* __restrict__ aip,
    const float* __restrict__ Hr, const float* __restrict__ Hi,
    u16* __restrict__ h_out, float* __restrict__ tail) {
  int tid = blockIdx.x * 256 + threadIdx.x;
  int c = tid & 1023;
  int chunk = (tid >> 10) & 63;
  int b = tid >> 16;
  float sp = log1pf(__expf(arp[c]));
  float aim = aip[c];
  size_t row0 = (size_t)b * 4096 + chunk * 64;
  size_t base = row0 * 1024 + c;
  float hr = Hr[tid], hi = Hi[tid];
#pragma unroll 4
  for (int i = 0; i < 64; ++i) {
    size_t idx = base + (size_t)i * 1024;
    float g = ga[idx];
    float mag = __expf(-8.f * g * sp);
    float s, co;
    __sincosf(aim * g, &s, &co);
    float ar = mag * co, ai = mag * s;
    float nhr = ar * hr - ai * hi + bf2f(xr[idx]);
    float nhi = ar * hi + ai * hr + bf2f(xi[idx]);
    hr = nhr; hi = nhi;
    size_t r = row0 + i;
    h_out[r * 2048 + c] = f2bf(hr);
    h_out[r * 2048 + 1024 + c] = f2bf(hi);
  }
  if (chunk == 63) {  // s = 4095
    tail[(size_t)b * 2048 + c] = hr;
    tail[(size_t)b * 2048 + 1024 + c] = hi;
  }
}

// ---------------------------------------------------------------- launch
static const size_t OFF_XH = 0;            // u16 [16384][2048] (later: h)
static const size_t OFF_GA = 67108864;     // f32 [16384][1024]  (first: XB u16 [16384][2048])
static const size_t OFF_XR = 134217728;    // u16 [16384][1024]
static const size_t OFF_XI = 167772160;    // u16 [16384][1024]
static const size_t OFF_WIT = 201326592;   // u16 [2048][2048]  W_in^T
static const size_t OFF_WOT = 209715200;   // u16 [2048][2048]  W_out^T
static const size_t OFF_WGT = 218103808;   // u16 [8][256][256] gate weights^T (gx|ga)
static const size_t OFF_AGR = 219152384;   // f32 [262144] chunk aggregates
static const size_t OFF_AGI = 220200960;
static const size_t OFF_AXR = 221249536;
static const size_t OFF_AXI = 222298112;
static const size_t OFF_HPR = 223346688;   // f32 [262144] chunk prefixes
static const size_t OFF_HPI = 224395264;

extern "C" void kernel_launch(void* const* d_in, const int* in_sizes, int n_in,
                              void* d_out, int out_size, void* d_ws, size_t ws_size,
                              hipStream_t stream) {
  const float* x    = (const float*)d_in[0];
  const float* arp  = (const float*)d_in[1];
  const float* aip  = (const float*)d_in[2];
  const float* W_in = (const float*)d_in[3];
  const float* b_in = (const float*)d_in[4];
  const float* Wg_x = (const float*)d_in[5];
  const float* bg_x = (const float*)d_in[6];
  const float* Wg_a = (const float*)d_in[7];
  const float* bg_a = (const float*)d_in[8];
  const float* W_out = (const float*)d_in[9];
  const float* b_out = (const float*)d_in[10];

  char* ws = (char*)d_ws;
  u16* XH = (u16*)(ws + OFF_XH);
  u16* XB = (u16*)(ws + OFF_GA);   // bf16 copy of x; dead once GEMM1 finishes
  float* GA = (float*)(ws + OFF_GA);
  u16* XR = (u16*)(ws + OFF_XR);
  u16* XI = (u16*)(ws + OFF_XI);
  u16* WIT = (u16*)(ws + OFF_WIT);
  u16* WOT = (u16*)(ws + OFF_WOT);
  u16* WGT = (u16*)(ws + OFF_WGT);
  float* AGR = (float*)(ws + OFF_AGR);
  float* AGI = (float*)(ws + OFF_AGI);
  float* AXR = (float*)(ws + OFF_AXR);
  float* AXI = (float*)(ws + OFF_AXI);
  float* HPR = (float*)(ws + OFF_HPR);
  float* HPI = (float*)(ws + OFF_HPI);

  float* y_out = (float*)d_out;
  float* h_last = (float*)d_out + (size_t)16384 * 2048;

  // x -> bf16
  convert_f32_bf16<<<16384, 256, 0, stream>>>(x, XB, (long)16384 * 2048);

  dim3 tb(32, 8);
  transpose_f32_bf16<<<dim3(64, 64, 1), tb, 0, stream>>>(W_in, WIT, 2048, 2048, 0, 0);
  transpose_f32_bf16<<<dim3(64, 64, 1), tb, 0, stream>>>(W_out, WOT, 2048, 2048, 0, 0);
  transpose_f32_bf16<<<dim3(4, 8, 8), tb, 0, stream>>>(Wg_x, WGT, 256, 128, 32768, 65536);
  transpose_f32_bf16<<<dim3(4, 8, 8), tb, 0, stream>>>(Wg_a, WGT + 32768, 256, 128, 32768, 65536);

  // x_h = x @ W_in + b_in  (bf16 out)
  gemm256_bt_bias<u16><<<512, 512, 0, stream>>>(XB, WIT, b_in, XH, 16384, 2048, 2048);
  // gates + a/x scan inputs (overwrites XB region with GA)
  gate_elem_kernel<<<dim3(128, 8), 256, 0, stream>>>(XH, WGT, bg_x, bg_a, arp, GA, XR, XI);
  // chunked complex scan
  scan_pass1<<<1024, 256, 0, stream>>>(GA, XR, XI, arp, aip, AGR, AGI, AXR, AXI);
  scan_pass2<<<16, 256, 0, stream>>>(AGR, AGI, AXR, AXI, HPR, HPI);
  scan_pass3<<<1024, 256, 0, stream>>>(GA, XR, XI, arp, aip, HPR, HPI, XH /*h aliases x_h*/, h_last);
  // y = h @ W_out + b_out  (fp32 out)
  gemm256_bt_bias<float><<<512, 512, 0, stream>>>(XH, WOT, b_out, y_out, 16384, 2048, 2048);
}

// Round 3
// 706.908 us; speedup vs baseline: 1.1772x; 1.0063x over previous
//
#include <hip/hip_runtime.h>
#include <hip/hip_bf16.h>

// RG-LRU forward, MI355X/gfx950.
// I/O dtype: fp32. Internally bf16 MFMA GEMMs, fp32 gate_a + fp32 scan state.
// R5: GEMM addressing fully hoisted (templated K, per-thread u32 offsets,
// SALU K-advance, XOR buffer toggle), MQ k-interleaved, vmcnt(4,4) race-tight.

typedef unsigned short u16;
typedef unsigned int u32;
typedef unsigned long long u64;
typedef __attribute__((ext_vector_type(8))) short short8;
typedef __attribute__((ext_vector_type(4))) float floatx4;

#define DEV __device__ __forceinline__

DEV float bf2f(u16 u) { union { u32 i; float f; } v; v.i = ((u32)u) << 16; return v.f; }
DEV u16 f2bf(float f) {
  union { float f; u32 i; } v; v.f = f;
  u32 r = v.i + 0x7fffu + ((v.i >> 16) & 1u);  // RNE
  return (u16)(r >> 16);
}
DEV float sigmoidf_(float x) { return 1.f / (1.f + __expf(-x)); }

#if __has_builtin(__builtin_amdgcn_global_load_lds)
#define USE_ASYNC_LDS 1
#endif

DEV void cp16(const void* g, void* l) {
#if defined(USE_ASYNC_LDS) && defined(__HIP_DEVICE_COMPILE__)
  __builtin_amdgcn_global_load_lds((const __attribute__((address_space(1))) u32*)g,
                                   (__attribute__((address_space(3))) u32*)l, 16, 0, 0);
#else
  *(short8*)l = *(const short8*)g;
#endif
}
#define WAIT_VM() asm volatile("s_waitcnt vmcnt(0)" ::: "memory")
#define LGKM0()  do { asm volatile("s_waitcnt lgkmcnt(0)" ::: "memory"); __builtin_amdgcn_sched_barrier(0); } while (0)
#define BAR()    __builtin_amdgcn_s_barrier()
#define VMC4()   asm volatile("s_waitcnt vmcnt(4)" ::: "memory")
#define SETP(p)  __builtin_amdgcn_s_setprio(p)

// ---------------------------------------------------------------- convert fp32 -> bf16
__global__ __launch_bounds__(256) void convert_f32_bf16(
    const float* __restrict__ src, u16* __restrict__ dst, long n) {
  long i = ((long)blockIdx.x * 256 + threadIdx.x) * 8;
  if (i >= n) return;
  float4 a = *(const float4*)(src + i);
  float4 b = *(const float4*)(src + i + 4);
  union { u16 u[8]; short8 v; } o;
  o.u[0] = f2bf(a.x); o.u[1] = f2bf(a.y); o.u[2] = f2bf(a.z); o.u[3] = f2bf(a.w);
  o.u[4] = f2bf(b.x); o.u[5] = f2bf(b.y); o.u[6] = f2bf(b.z); o.u[7] = f2bf(b.w);
  *(short8*)(dst + i) = o.v;
}

// ---------------------------------------------------------------- transpose + convert
__global__ __launch_bounds__(256) void transpose_f32_bf16(
    const float* __restrict__ src, u16* __restrict__ dst, int R, int C,
    long sBatch, long dBatch) {
  __shared__ u16 tile[32][33];
  const int n = blockIdx.z;
  src += (long)n * sBatch;
  dst += (long)n * dBatch;
  const int c0 = blockIdx.x * 32, r0 = blockIdx.y * 32;
  const int tx = threadIdx.x, ty = threadIdx.y;  // (32,8)
#pragma unroll
  for (int i = 0; i < 32; i += 8)
    tile[ty + i][tx] = f2bf(src[(long)(r0 + ty + i) * C + c0 + tx]);
  __syncthreads();
#pragma unroll
  for (int i = 0; i < 32; i += 8) dst[(long)(c0 + ty + i) * R + r0 + tx] = tile[tx][ty + i];
}

// ---------------------------------------------------------------- 256^2 8-phase GEMM
// Same pipeline shape as R4 (stage gap / barrier / lgkm0 / reads-next + 16 MFMA
// / counted vmcnt / barrier) but with ALL address math hoisted:
//  - per-thread u32 global stage offsets (templated K); K-advance is SALU.
//  - per-thread u32 LDS stage/read base offsets; buffer select = XOR 0x8000.
//  - fragment index folds into the ds_read 16-bit offset immediate.
// vmcnt(4) at end of p1 and p2: every staged half has >=2 phases of flight and
// a covering counted wait before its first reader (race-closed, never 0 until
// the tail). MQ issues 8 independent k0 MFMAs then 8 k1 (no dependent pairs).
#define MQK(MH, NH)                                                                  \
  {                                                                                  \
    _Pragma("unroll") for (int mi = 0; mi < 4; ++mi)                                 \
        _Pragma("unroll") for (int nj = 0; nj < 2; ++nj)                             \
      acc[(MH)*4 + mi][(NH)*2 + nj] = __builtin_amdgcn_mfma_f32_16x16x32_bf16(       \
          af[(MH)*4 + mi][0], bf[(NH)*2 + nj][0], acc[(MH)*4 + mi][(NH)*2 + nj],     \
          0, 0, 0);                                                                  \
    _Pragma("unroll") for (int mi = 0; mi < 4; ++mi)                                 \
        _Pragma("unroll") for (int nj = 0; nj < 2; ++nj)                             \
      acc[(MH)*4 + mi][(NH)*2 + nj] = __builtin_amdgcn_mfma_f32_16x16x32_bf16(       \
          af[(MH)*4 + mi][1], bf[(NH)*2 + nj][1], acc[(MH)*4 + mi][(NH)*2 + nj],     \
          0, 0, 0);                                                                  \
  }

#define RDA(m0_, BO)                                                                 \
  {                                                                                  \
    _Pragma("unroll") for (int mi = (m0_); mi < (m0_) + 4; ++mi) {                   \
      af[mi][0] = *(const short8*)((const char*)SM + ((aRd0 ^ (BO)) + mi * 2048));   \
      af[mi][1] = *(const short8*)((const char*)SM + ((aRd1 ^ (BO)) + mi * 2048));   \
    }                                                                                \
  }
#define RDB(n0_, BO)                                                                 \
  {                                                                                  \
    _Pragma("unroll") for (int nj = (n0_); nj < (n0_) + 2; ++nj) {                   \
      bf[nj][0] = *(const short8*)((const char*)SM + ((bRd0 ^ (BO)) + nj * 2048));   \
      bf[nj][1] = *(const short8*)((const char*)SM + ((bRd1 ^ (BO)) + nj * 2048));   \
    }                                                                                \
  }

template <typename OutT, int KK>
__global__ __launch_bounds__(512, 2) void gemm256_bt_bias(
    const u16* __restrict__ A, const u16* __restrict__ BT,
    const float* __restrict__ bias, OutT* __restrict__ C, int M, int N) {
  constexpr int NT = KK >> 6;  // K-tiles (BK=64); assumes NT >= 3
  __shared__ __align__(16) u16 SM[65536];  // 128 KB: As(2x32KB) | Bs(2x32KB)
  const int mt = M >> 8;
  // T1: bijective XCD swizzle (grid % 8 == 0); bm-fastest -> each XCD owns one
  // bn column (B panel L2-resident), all XCDs sweep A in the same order.
  const int cpx = gridDim.x >> 3;
  const int bid = blockIdx.x;
  const int wg = (bid & 7) * cpx + (bid >> 3);
  const int bm = wg % mt, bn = wg / mt;
  const int m0 = bm << 8, n0 = bn << 8;
  const int tid = threadIdx.x;
  const int lane = tid & 63, wid = tid >> 6;
  const int wr = wid >> 2, wc = wid & 3;  // wave tile: rows wr*128, cols wc*64
  const int lq = lane >> 4, lm = lane & 15;
  const int sz = lm & 7;

  // ---- hoisted per-thread offsets (all constant across the K-loop) ----
  // stage: roles 0=A.h0 1=A.h1 2=B.h0 3=B.h1; l=0 row block, l=1 = +64 rows.
  u32 goffA0, goffA1, goffB0, goffB1;  // global byte offsets (l=0)
  u32 lofA0, lofA1, lofB0, lofB1;      // LDS byte offsets (buffer 0, l=0)
  {
    const int rowl = tid >> 3, gch = (tid & 7) ^ (rowl & 7);
    goffA0 = (u32)(((size_t)(m0 + rowl) * KK + (gch << 3)) * 2);
    goffA1 = (u32)(((size_t)(m0 + 128 + rowl) * KK + (gch << 3)) * 2);
    goffB0 = (u32)(((size_t)(n0 + rowl) * KK + (gch << 3)) * 2);
    goffB1 = (u32)(((size_t)(n0 + 128 + rowl) * KK + (gch << 3)) * 2);
    const u32 sl = (u32)tid * 16;
    lofA0 = sl; lofA1 = sl + 16384; lofB0 = sl + 65536; lofB1 = sl + 81920;
  }
  // ds_read bases (buffer 0); k-half1 = XOR 64 (single-bit), frag idx = imm.
  const u32 aRd0 = (u32)((((wr << 7) + lm) << 7) + ((lq ^ sz) << 4));
  const u32 aRd1 = aRd0 ^ 64u;
  const u32 bRd0 = (u32)(65536 + (((wc << 6) + lm) << 7) + ((lq ^ sz) << 4));
  const u32 bRd1 = bRd0 ^ 64u;

  auto stage2 = [&](u32 go, const char* base, u32 lo, u32 bo) {
    cp16(base + go, (char*)SM + (lo ^ bo));
    cp16(base + go + 64 * KK * 2, (char*)SM + ((lo ^ bo) + 8192));
  };
#define SBA(t) ((const char*)A + ((size_t)(t) << 7))
#define SBB(t) ((const char*)BT + ((size_t)(t) << 7))

  floatx4 acc[8][4];
#pragma unroll
  for (int i = 0; i < 8; ++i)
#pragma unroll
    for (int j = 0; j < 4; ++j) { acc[i][j].x = 0.f; acc[i][j].y = 0.f; acc[i][j].z = 0.f; acc[i][j].w = 0.f; }
  short8 af[8][2], bf[4][2];

  // prologue: tile0 all 4 halves + tile1 {A0,B0,A1}; drain tile0 -> vmcnt(6)
  stage2(goffA0, SBA(0), lofA0, 0);
  stage2(goffB0, SBB(0), lofB0, 0);
  stage2(goffA1, SBA(0), lofA1, 0);
  stage2(goffB1, SBB(0), lofB1, 0);
  stage2(goffA0, SBA(1), lofA0, 0x8000u);
  stage2(goffB0, SBB(1), lofB0, 0x8000u);
  stage2(goffA1, SBA(1), lofA1, 0x8000u);
  asm volatile("s_waitcnt vmcnt(6)" ::: "memory");
  BAR();
  RDA(0, 0u);  // af0-3 (tile0)
  RDB(0, 0u);  // bf01 (tile0)

  for (int T = 0; T < NT - 2; ++T) {
    const u32 bo = (u32)((T & 1) << 15), bq = bo ^ 0x8000u;
    // p0: MQ(0,0) || read bf23(T); stage (T+1).B1
    stage2(goffB1, SBB(T + 1), lofB1, bq);
    BAR(); LGKM0();
    RDB(2, bo);
    SETP(1); MQK(0, 0); SETP(0);
    BAR();
    // p1: MQ(0,1) || read af4-7(T); stage (T+2).A0; vmcnt(4)
    stage2(goffA0, SBA(T + 2), lofA0, bo);
    BAR(); LGKM0();
    RDA(4, bo);
    SETP(1); MQK(0, 1); SETP(0);
    VMC4();
    BAR();
    // p2: MQ(1,0) || read af0-3(T+1); stage (T+2).B0; vmcnt(4)
    stage2(goffB0, SBB(T + 2), lofB0, bo);
    BAR(); LGKM0();
    RDA(0, bq);
    SETP(1); MQK(1, 0); SETP(0);
    VMC4();
    BAR();
    // p3: MQ(1,1) || read bf01(T+1); stage (T+2).A1
    stage2(goffA1, SBA(T + 2), lofA1, bo);
    BAR(); LGKM0();
    RDB(0, bq);
    SETP(1); MQK(1, 1); SETP(0);
    BAR();
  }
  {  // tail tile NT-2: stage only (NT-1).B1; drain all by end of p1
    const int T = NT - 2;
    const u32 bo = (u32)((T & 1) << 15), bq = bo ^ 0x8000u;
    stage2(goffB1, SBB(T + 1), lofB1, bq);
    BAR(); LGKM0(); RDB(2, bo); SETP(1); MQK(0, 0); SETP(0); BAR();
    BAR(); LGKM0(); RDA(4, bo); SETP(1); MQK(0, 1); SETP(0); WAIT_VM(); BAR();
    BAR(); LGKM0(); RDA(0, bq); SETP(1); MQK(1, 0); SETP(0); BAR();
    BAR(); LGKM0(); RDB(0, bq); SETP(1); MQK(1, 1); SETP(0); BAR();
  }
  {  // tail tile NT-1: no staging, no next-tile reads
    const u32 bo = (u32)(((NT - 1) & 1) << 15);
    BAR(); LGKM0(); RDB(2, bo); SETP(1); MQK(0, 0); SETP(0); BAR();
    BAR(); LGKM0(); RDA(4, bo); SETP(1); MQK(0, 1); SETP(0); BAR();
    BAR(); LGKM0(); SETP(1); MQK(1, 0); SETP(0); BAR();
    BAR(); LGKM0(); SETP(1); MQK(1, 1); SETP(0); BAR();
  }
#undef SBA
#undef SBB

  // Epilogue: stage C through LDS (4 slabs of 64 rows x 256 cols, stride 260 f32)
  // -> full coalesced row writes; stride 260 keeps ds traffic at 2-way (free).
  float bv[4];
#pragma unroll
  for (int nj = 0; nj < 4; ++nj) bv[nj] = bias[n0 + (wc << 6) + nj * 16 + lm];
  float* Cs = (float*)SM;  // 64*260*4 = 66560 B of the 128 KB
#pragma unroll
  for (int s = 0; s < 4; ++s) {
    __syncthreads();
    if (wr == (s >> 1)) {
#pragma unroll
      for (int mi2 = 0; mi2 < 4; ++mi2) {
        const int mi = ((s & 1) << 2) + mi2;
#pragma unroll
        for (int nj = 0; nj < 4; ++nj)
#pragma unroll
          for (int rr = 0; rr < 4; ++rr)
            Cs[(mi2 * 16 + lq * 4 + rr) * 260 + (wc << 6) + nj * 16 + lm] =
                acc[mi][nj][rr] + bv[nj];
      }
    }
    __syncthreads();
#pragma unroll
    for (int w = 0; w < 8; ++w) {
      int fi = (w << 9) + tid;  // 4096 float4 chunks; each wave writes one row
      int rl = fi >> 6, cc = fi & 63;
      float4 v = *(const float4*)&Cs[rl * 260 + (cc << 2)];
      size_t grow = (size_t)(m0 + (s << 6) + rl) * N + n0 + (cc << 2);
      if constexpr (sizeof(OutT) == 2) {
        union { u16 u[4]; u64 q; } o;
        o.u[0] = f2bf(v.x); o.u[1] = f2bf(v.y); o.u[2] = f2bf(v.z); o.u[3] = f2bf(v.w);
        *(u64*)((u16*)C + grow) = o.q;
      } else {
        *(float4*)((float*)C + grow) = v;
      }
    }
  }
}

// ---------------------------------------------------------------- gates + elementwise
__global__ __launch_bounds__(256, 2) void gate_elem_kernel(
    const u16* __restrict__ xh, const u16* __restrict__ wgt,
    const float* __restrict__ bgx, const float* __restrict__ bga,
    const float* __restrict__ arp,
    float* __restrict__ ga_out, u16* __restrict__ xr_out, u16* __restrict__ xi_out) {
  __shared__ __align__(16) u16 As[128 * 64];  // 16 KB
  __shared__ __align__(16) u16 Bs[256 * 64];  // 32 KB

  const int m0 = blockIdx.x << 7;
  const int blk = blockIdx.y;
  const int tid = threadIdx.x;
  const int lane = tid & 63, wid = tid >> 6;
  const int wm = (wid & 1) << 6, wn = (wid >> 1) << 6;
  const int lq = lane >> 4, lm = lane & 15;

  floatx4 acc[4][8];
#pragma unroll
  for (int i = 0; i < 4; ++i)
#pragma unroll
    for (int j = 0; j < 8; ++j) { acc[i][j].x = 0.f; acc[i][j].y = 0.f; acc[i][j].z = 0.f; acc[i][j].w = 0.f; }

  const u16* Ag = xh + (size_t)m0 * 2048 + blk * 256;  // row stride 2048
  const u16* Bg = wgt + (size_t)blk * 65536;           // [256][256] row-major

  for (int kt = 0; kt < 256; kt += 64) {
#pragma unroll
    for (int j = 0; j < 4; ++j) {
      int slot = (j << 8) + tid;
      int row = slot >> 3, ch = slot & 7;
      int gch = ch ^ (row & 7);
      cp16(Ag + (size_t)row * 2048 + kt + (gch << 3), (char*)As + slot * 16);
    }
#pragma unroll
    for (int j = 0; j < 8; ++j) {
      int slot = (j << 8) + tid;
      int row = slot >> 3, ch = slot & 7;
      int gch = ch ^ (row & 7);
      cp16(Bg + (size_t)row * 256 + kt + (gch << 3), (char*)Bs + slot * 16);
    }
    WAIT_VM();
    __syncthreads();
#pragma unroll
    for (int kk = 0; kk < 64; kk += 32) {
      const int lc = (kk >> 3) + lq;
      short8 af[4], bfr[8];
#pragma unroll
      for (int mi = 0; mi < 4; ++mi) {
        int r = wm + mi * 16 + lm;
        af[mi] = *(const short8*)&As[r * 64 + ((lc ^ (r & 7)) << 3)];
      }
#pragma unroll
      for (int ni = 0; ni < 8; ++ni) {
        int r = (ni < 4) ? (wn + ni * 16 + lm) : (128 + wn + (ni - 4) * 16 + lm);
        bfr[ni] = *(const short8*)&Bs[r * 64 + ((lc ^ (r & 7)) << 3)];
      }
#pragma unroll
      for (int mi = 0; mi < 4; ++mi)
#pragma unroll
        for (int ni = 0; ni < 8; ++ni)
          acc[mi][ni] = __builtin_amdgcn_mfma_f32_16x16x32_bf16(af[mi], bfr[ni], acc[mi][ni], 0, 0, 0);
    }
    __syncthreads();
  }

#pragma unroll
  for (int ni = 0; ni < 4; ++ni) {
    const int c = (blk << 7) + wn + ni * 16 + lm;
    const float bxv = bgx[c], bav = bga[c];
    const float sp = log1pf(__expf(arp[c]));  // softplus(a_real_param)
#pragma unroll
    for (int mi = 0; mi < 4; ++mi) {
      const size_t rowg0 = (size_t)m0 + wm + mi * 16 + lq * 4;
#pragma unroll
      for (int r = 0; r < 4; ++r) {
        const size_t rowg = rowg0 + r;
        float gxv = sigmoidf_(acc[mi][ni][r] + bxv);
        float gav = sigmoidf_(acc[mi][ni + 4][r] + bav);
        float mag = __expf(-8.f * gav * sp);
        float norm = sqrtf(fmaxf(1.f - mag * mag, 0.f));
        float f = norm * gxv;
        ga_out[rowg * 1024 + c] = gav;  // fp32: scan precision requires it
        xr_out[rowg * 1024 + c] = f2bf(f * bf2f(xh[rowg * 2048 + c]));
        xi_out[rowg * 1024 + c] = f2bf(f * bf2f(xh[rowg * 2048 + 1024 + c]));
      }
    }
  }
}

// ---------------------------------------------------------------- scan (chunk=64, 64 chunks)
__global__ __launch_bounds__(256) void scan_pass1(
    const float* __restrict__ ga, const u16* __restrict__ xr, const u16* __restrict__ xi,
    const float* __restrict__ arp, const float* __restrict__ aip,
    float* __restrict__ Ar, float* __restrict__ Ai,
    float* __restrict__ Xr, float* __restrict__ Xi) {
  int tid = blockIdx.x * 256 + threadIdx.x;  // [0, 4*64*1024)
  int c = tid & 1023;
  int chunk = (tid >> 10) & 63;
  int b = tid >> 16;
  float sp = log1pf(__expf(arp[c]));
  float aim = aip[c];
  size_t base = ((size_t)b * 4096 + chunk * 64) * 1024 + c;
  float Arr = 1.f, Aii = 0.f, Xrr = 0.f, Xii = 0.f;
#pragma unroll 4
  for (int i = 0; i < 64; ++i) {
    size_t idx = base + (size_t)i * 1024;
    float g = ga[idx];
    float mag = __expf(-8.f * g * sp);
    float s, co;
    __sincosf(aim * g, &s, &co);
    float ar = mag * co, ai = mag * s;
    float nxr = ar * Xrr - ai * Xii + bf2f(xr[idx]);
    float nxi = ar * Xii + ai * Xrr + bf2f(xi[idx]);
    Xrr = nxr; Xii = nxi;
    float nar = ar * Arr - ai * Aii;
    float nai = ar * Aii + ai * Arr;
    Arr = nar; Aii = nai;
  }
  Ar[tid] = Arr; Ai[tid] = Aii; Xr[tid] = Xrr; Xi[tid] = Xii;
}

__global__ __launch_bounds__(256) void scan_pass2(
    const float* __restrict__ Ar, const float* __restrict__ Ai,
    const float* __restrict__ Xr, const float* __restrict__ Xi,
    float* __restrict__ Hr, float* __restrict__ Hi) {
  int tid = blockIdx.x * 256 + threadIdx.x;  // [0, 4096)
  int c = tid & 1023, b = tid >> 10;
  float hr = 0.f, hi = 0.f;
  for (int j = 0; j < 64; ++j) {
    int idx = (b << 16) + (j << 10) + c;
    Hr[idx] = hr; Hi[idx] = hi;
    float ar = Ar[idx], ai = Ai[idx];
    float nhr = ar * hr - ai * hi + Xr[idx];
    float nhi = ar * hi + ai * hr + Xi[idx];
    hr = nhr; hi = nhi;
  }
}

__global__ __launch_bounds__(256) void scan_pass3(
    const float* __restrict__ ga, const u16* __restrict__ xr, const u16* __restrict__ xi,
    const float* __restrict__ arp, const float* __restrict__ aip,
    const float* __restrict__ Hr, const float* __restrict__ Hi,
    u16* __restrict__ h_out, float* __restrict__ tail) {
  int tid = blockIdx.x * 256 + threadIdx.x;
  int c = tid & 1023;
  int chunk = (tid >> 10) & 63;
  int b = tid >> 16;
  float sp = log1pf(__expf(arp[c]));
  float aim = aip[c];
  size_t row0 = (size_t)b * 4096 + chunk * 64;
  size_t base = row0 * 1024 + c;
  float hr = Hr[tid], hi = Hi[tid];
#pragma unroll 4
  for (int i = 0; i < 64; ++i) {
    size_t idx = base + (size_t)i * 1024;
    float g = ga[idx];
    float mag = __expf(-8.f * g * sp);
    float s, co;
    __sincosf(aim * g, &s, &co);
    float ar = mag * co, ai = mag * s;
    float nhr = ar * hr - ai * hi + bf2f(xr[idx]);
    float nhi = ar * hi + ai * hr + bf2f(xi[idx]);
    hr = nhr; hi = nhi;
    size_t r = row0 + i;
    h_out[r * 2048 + c] = f2bf(hr);
    h_out[r * 2048 + 1024 + c] = f2bf(hi);
  }
  if (chunk == 63) {  // s = 4095
    tail[(size_t)b * 2048 + c] = hr;
    tail[(size_t)b * 2048 + 1024 + c] = hi;
  }
}

// ---------------------------------------------------------------- launch
static const size_t OFF_XH = 0;            // u16 [16384][2048] (later: h)
static const size_t OFF_GA = 67108864;     // f32 [16384][1024]  (first: XB u16 [16384][2048])
static const size_t OFF_XR = 134217728;    // u16 [16384][1024]
static const size_t OFF_XI = 167772160;    // u16 [16384][1024]
static const size_t OFF_WIT = 201326592;   // u16 [2048][2048]  W_in^T
static const size_t OFF_WOT = 209715200;   // u16 [2048][2048]  W_out^T
static const size_t OFF_WGT = 218103808;   // u16 [8][256][256] gate weights^T (gx|ga)
static const size_t OFF_AGR = 219152384;   // f32 [262144] chunk aggregates
static const size_t OFF_AGI = 220200960;
static const size_t OFF_AXR = 221249536;
static const size_t OFF_AXI = 222298112;
static const size_t OFF_HPR = 223346688;   // f32 [262144] chunk prefixes
static const size_t OFF_HPI = 224395264;

extern "C" void kernel_launch(void* const* d_in, const int* in_sizes, int n_in,
                              void* d_out, int out_size, void* d_ws, size_t ws_size,
                              hipStream_t stream) {
  const float* x    = (const float*)d_in[0];
  const float* arp  = (const float*)d_in[1];
  const float* aip  = (const float*)d_in[2];
  const float* W_in = (const float*)d_in[3];
  const float* b_in = (const float*)d_in[4];
  const float* Wg_x = (const float*)d_in[5];
  const float* bg_x = (const float*)d_in[6];
  const float* Wg_a = (const float*)d_in[7];
  const float* bg_a = (const float*)d_in[8];
  const float* W_out = (const float*)d_in[9];
  const float* b_out = (const float*)d_in[10];

  char* ws = (char*)d_ws;
  u16* XH = (u16*)(ws + OFF_XH);
  u16* XB = (u16*)(ws + OFF_GA);   // bf16 copy of x; dead once GEMM1 finishes
  float* GA = (float*)(ws + OFF_GA);
  u16* XR = (u16*)(ws + OFF_XR);
  u16* XI = (u16*)(ws + OFF_XI);
  u16* WIT = (u16*)(ws + OFF_WIT);
  u16* WOT = (u16*)(ws + OFF_WOT);
  u16* WGT = (u16*)(ws + OFF_WGT);
  float* AGR = (float*)(ws + OFF_AGR);
  float* AGI = (float*)(ws + OFF_AGI);
  float* AXR = (float*)(ws + OFF_AXR);
  float* AXI = (float*)(ws + OFF_AXI);
  float* HPR = (float*)(ws + OFF_HPR);
  float* HPI = (float*)(ws + OFF_HPI);

  float* y_out = (float*)d_out;
  float* h_last = (float*)d_out + (size_t)16384 * 2048;

  // x -> bf16
  convert_f32_bf16<<<16384, 256, 0, stream>>>(x, XB, (long)16384 * 2048);

  dim3 tb(32, 8);
  transpose_f32_bf16<<<dim3(64, 64, 1), tb, 0, stream>>>(W_in, WIT, 2048, 2048, 0, 0);
  transpose_f32_bf16<<<dim3(64, 64, 1), tb, 0, stream>>>(W_out, WOT, 2048, 2048, 0, 0);
  transpose_f32_bf16<<<dim3(4, 8, 8), tb, 0, stream>>>(Wg_x, WGT, 256, 128, 32768, 65536);
  transpose_f32_bf16<<<dim3(4, 8, 8), tb, 0, stream>>>(Wg_a, WGT + 32768, 256, 128, 32768, 65536);

  // x_h = x @ W_in + b_in  (bf16 out)
  gemm256_bt_bias<u16, 2048><<<512, 512, 0, stream>>>(XB, WIT, b_in, XH, 16384, 2048);
  // gates + a/x scan inputs (overwrites XB region with GA)
  gate_elem_kernel<<<dim3(128, 8), 256, 0, stream>>>(XH, WGT, bg_x, bg_a, arp, GA, XR, XI);
  // chunked complex scan
  scan_pass1<<<1024, 256, 0, stream>>>(GA, XR, XI, arp, aip, AGR, AGI, AXR, AXI);
  scan_pass2<<<16, 256, 0, stream>>>(AGR, AGI, AXR, AXI, HPR, HPI);
  scan_pass3<<<1024, 256, 0, stream>>>(GA, XR, XI, arp, aip, HPR, HPI, XH /*h aliases x_h*/, h_last);
  // y = h @ W_out + b_out  (fp32 out)
  gemm256_bt_bias<float, 2048><<<512, 512, 0, stream>>>(XH, WOT, b_out, y_out, 16384, 2048);
}

// Round 4
// 670.363 us; speedup vs baseline: 1.2414x; 1.0545x over previous
//
#include <hip/hip_runtime.h>
#include <hip/hip_bf16.h>

// RG-LRU forward, MI355X/gfx950.
// I/O dtype: fp32. Internally bf16 MFMA GEMMs, fp32 gate_a + fp32 scan state.
// R6: (1) GEMM phases get sched_group_barrier-pinned DS_READ/MFMA interleave
// (issue-clustering fix: reads no longer drain before MFMA issue);
// (2) gate_elem epilogue LDS-staged w/ full-line vectorized writes;
// (3) scan passes c2-vectorized (8B/lane loads, u32 bf16-pair stores).

typedef unsigned short u16;
typedef unsigned int u32;
typedef unsigned long long u64;
typedef __attribute__((ext_vector_type(8))) short short8;
typedef __attribute__((ext_vector_type(4))) float floatx4;

#define DEV __device__ __forceinline__

DEV float bf2f(u16 u) { union { u32 i; float f; } v; v.i = ((u32)u) << 16; return v.f; }
DEV u16 f2bf(float f) {
  union { float f; u32 i; } v; v.f = f;
  u32 r = v.i + 0x7fffu + ((v.i >> 16) & 1u);  // RNE
  return (u16)(r >> 16);
}
DEV float sigmoidf_(float x) { return 1.f / (1.f + __expf(-x)); }

#if __has_builtin(__builtin_amdgcn_global_load_lds)
#define USE_ASYNC_LDS 1
#endif

DEV void cp16(const void* g, void* l) {
#if defined(USE_ASYNC_LDS) && defined(__HIP_DEVICE_COMPILE__)
  __builtin_amdgcn_global_load_lds((const __attribute__((address_space(1))) u32*)g,
                                   (__attribute__((address_space(3))) u32*)l, 16, 0, 0);
#else
  *(short8*)l = *(const short8*)g;
#endif
}
#define WAIT_VM() asm volatile("s_waitcnt vmcnt(0)" ::: "memory")
#define LGKM0()  do { asm volatile("s_waitcnt lgkmcnt(0)" ::: "memory"); __builtin_amdgcn_sched_barrier(0); } while (0)
#define BAR()    __builtin_amdgcn_s_barrier()
#define VMC4()   asm volatile("s_waitcnt vmcnt(4)" ::: "memory")
#define SETP(p)  __builtin_amdgcn_s_setprio(p)
#define SGB(m, n) __builtin_amdgcn_sched_group_barrier(m, n, 0)

// Pin an interleave of R ds_reads among 16 MFMAs: R x {1 DS_READ, 16/R MFMA}.
template <int R> DEV void sgbIL() {
#pragma unroll
  for (int i = 0; i < R; ++i) { SGB(0x100, 1); SGB(0x8, 16 / R); }
}

// ---------------------------------------------------------------- convert fp32 -> bf16
__global__ __launch_bounds__(256) void convert_f32_bf16(
    const float* __restrict__ src, u16* __restrict__ dst, long n) {
  long i = ((long)blockIdx.x * 256 + threadIdx.x) * 8;
  if (i >= n) return;
  float4 a = *(const float4*)(src + i);
  float4 b = *(const float4*)(src + i + 4);
  union { u16 u[8]; short8 v; } o;
  o.u[0] = f2bf(a.x); o.u[1] = f2bf(a.y); o.u[2] = f2bf(a.z); o.u[3] = f2bf(a.w);
  o.u[4] = f2bf(b.x); o.u[5] = f2bf(b.y); o.u[6] = f2bf(b.z); o.u[7] = f2bf(b.w);
  *(short8*)(dst + i) = o.v;
}

// ---------------------------------------------------------------- transpose + convert
__global__ __launch_bounds__(256) void transpose_f32_bf16(
    const float* __restrict__ src, u16* __restrict__ dst, int R, int C,
    long sBatch, long dBatch) {
  __shared__ u16 tile[32][33];
  const int n = blockIdx.z;
  src += (long)n * sBatch;
  dst += (long)n * dBatch;
  const int c0 = blockIdx.x * 32, r0 = blockIdx.y * 32;
  const int tx = threadIdx.x, ty = threadIdx.y;  // (32,8)
#pragma unroll
  for (int i = 0; i < 32; i += 8)
    tile[ty + i][tx] = f2bf(src[(long)(r0 + ty + i) * C + c0 + tx]);
  __syncthreads();
#pragma unroll
  for (int i = 0; i < 32; i += 8) dst[(long)(c0 + ty + i) * R + r0 + tx] = tile[tx][ty + i];
}

// ---------------------------------------------------------------- 256^2 8-phase GEMM
// R5 pipeline (hoisted addressing, vmcnt(4,4)) + R6 sched_group_barrier pinned
// DS_READ/MFMA interleave per phase (reads feed the LDS pipe WHILE the matrix
// pipe runs, instead of draining first).
#define MQK(MH, NH)                                                                  \
  {                                                                                  \
    _Pragma("unroll") for (int mi = 0; mi < 4; ++mi)                                 \
        _Pragma("unroll") for (int nj = 0; nj < 2; ++nj)                             \
      acc[(MH)*4 + mi][(NH)*2 + nj] = __builtin_amdgcn_mfma_f32_16x16x32_bf16(       \
          af[(MH)*4 + mi][0], bf[(NH)*2 + nj][0], acc[(MH)*4 + mi][(NH)*2 + nj],     \
          0, 0, 0);                                                                  \
    _Pragma("unroll") for (int mi = 0; mi < 4; ++mi)                                 \
        _Pragma("unroll") for (int nj = 0; nj < 2; ++nj)                             \
      acc[(MH)*4 + mi][(NH)*2 + nj] = __builtin_amdgcn_mfma_f32_16x16x32_bf16(       \
          af[(MH)*4 + mi][1], bf[(NH)*2 + nj][1], acc[(MH)*4 + mi][(NH)*2 + nj],     \
          0, 0, 0);                                                                  \
  }

#define RDA(m0_, BO)                                                                 \
  {                                                                                  \
    _Pragma("unroll") for (int mi = (m0_); mi < (m0_) + 4; ++mi) {                   \
      af[mi][0] = *(const short8*)((const char*)SM + ((aRd0 ^ (BO)) + mi * 2048));   \
      af[mi][1] = *(const short8*)((const char*)SM + ((aRd1 ^ (BO)) + mi * 2048));   \
    }                                                                                \
  }
#define RDB(n0_, BO)                                                                 \
  {                                                                                  \
    _Pragma("unroll") for (int nj = (n0_); nj < (n0_) + 2; ++nj) {                   \
      bf[nj][0] = *(const short8*)((const char*)SM + ((bRd0 ^ (BO)) + nj * 2048));   \
      bf[nj][1] = *(const short8*)((const char*)SM + ((bRd1 ^ (BO)) + nj * 2048));   \
    }                                                                                \
  }

template <typename OutT, int KK>
__global__ __launch_bounds__(512, 2) void gemm256_bt_bias(
    const u16* __restrict__ A, const u16* __restrict__ BT,
    const float* __restrict__ bias, OutT* __restrict__ C, int M, int N) {
  constexpr int NT = KK >> 6;  // K-tiles (BK=64); assumes NT >= 3
  __shared__ __align__(16) u16 SM[65536];  // 128 KB: As(2x32KB) | Bs(2x32KB)
  const int mt = M >> 8;
  const int cpx = gridDim.x >> 3;
  const int bid = blockIdx.x;
  const int wg = (bid & 7) * cpx + (bid >> 3);
  const int bm = wg % mt, bn = wg / mt;
  const int m0 = bm << 8, n0 = bn << 8;
  const int tid = threadIdx.x;
  const int lane = tid & 63, wid = tid >> 6;
  const int wr = wid >> 2, wc = wid & 3;  // wave tile: rows wr*128, cols wc*64
  const int lq = lane >> 4, lm = lane & 15;
  const int sz = lm & 7;

  u32 goffA0, goffA1, goffB0, goffB1;  // global byte offsets (l=0)
  u32 lofA0, lofA1, lofB0, lofB1;      // LDS byte offsets (buffer 0, l=0)
  {
    const int rowl = tid >> 3, gch = (tid & 7) ^ (rowl & 7);
    goffA0 = (u32)(((size_t)(m0 + rowl) * KK + (gch << 3)) * 2);
    goffA1 = (u32)(((size_t)(m0 + 128 + rowl) * KK + (gch << 3)) * 2);
    goffB0 = (u32)(((size_t)(n0 + rowl) * KK + (gch << 3)) * 2);
    goffB1 = (u32)(((size_t)(n0 + 128 + rowl) * KK + (gch << 3)) * 2);
    const u32 sl = (u32)tid * 16;
    lofA0 = sl; lofA1 = sl + 16384; lofB0 = sl + 65536; lofB1 = sl + 81920;
  }
  const u32 aRd0 = (u32)((((wr << 7) + lm) << 7) + ((lq ^ sz) << 4));
  const u32 aRd1 = aRd0 ^ 64u;
  const u32 bRd0 = (u32)(65536 + (((wc << 6) + lm) << 7) + ((lq ^ sz) << 4));
  const u32 bRd1 = bRd0 ^ 64u;

  auto stage2 = [&](u32 go, const char* base, u32 lo, u32 bo) {
    cp16(base + go, (char*)SM + (lo ^ bo));
    cp16(base + go + 64 * KK * 2, (char*)SM + ((lo ^ bo) + 8192));
  };
#define SBA(t) ((const char*)A + ((size_t)(t) << 7))
#define SBB(t) ((const char*)BT + ((size_t)(t) << 7))

  floatx4 acc[8][4];
#pragma unroll
  for (int i = 0; i < 8; ++i)
#pragma unroll
    for (int j = 0; j < 4; ++j) { acc[i][j].x = 0.f; acc[i][j].y = 0.f; acc[i][j].z = 0.f; acc[i][j].w = 0.f; }
  short8 af[8][2], bf[4][2];

  // prologue: tile0 all 4 halves + tile1 {A0,B0,A1}; drain tile0 -> vmcnt(6)
  stage2(goffA0, SBA(0), lofA0, 0);
  stage2(goffB0, SBB(0), lofB0, 0);
  stage2(goffA1, SBA(0), lofA1, 0);
  stage2(goffB1, SBB(0), lofB1, 0);
  stage2(goffA0, SBA(1), lofA0, 0x8000u);
  stage2(goffB0, SBB(1), lofB0, 0x8000u);
  stage2(goffA1, SBA(1), lofA1, 0x8000u);
  asm volatile("s_waitcnt vmcnt(6)" ::: "memory");
  BAR();
  RDA(0, 0u);  // af0-3 (tile0)
  RDB(0, 0u);  // bf01 (tile0)

  for (int T = 0; T < NT - 2; ++T) {
    const u32 bo = (u32)((T & 1) << 15), bq = bo ^ 0x8000u;
    // p0: MQ(0,0) || read bf23(T); stage (T+1).B1
    stage2(goffB1, SBB(T + 1), lofB1, bq);
    BAR(); LGKM0();
    RDB(2, bo);
    SETP(1); MQK(0, 0); SETP(0);
    sgbIL<4>();
    BAR();
    // p1: MQ(0,1) || read af4-7(T); stage (T+2).A0; vmcnt(4)
    stage2(goffA0, SBA(T + 2), lofA0, bo);
    BAR(); LGKM0();
    RDA(4, bo);
    SETP(1); MQK(0, 1); SETP(0);
    sgbIL<8>();
    VMC4();
    BAR();
    // p2: MQ(1,0) || read af0-3(T+1); stage (T+2).B0; vmcnt(4)
    stage2(goffB0, SBB(T + 2), lofB0, bo);
    BAR(); LGKM0();
    RDA(0, bq);
    SETP(1); MQK(1, 0); SETP(0);
    sgbIL<8>();
    VMC4();
    BAR();
    // p3: MQ(1,1) || read bf01(T+1); stage (T+2).A1
    stage2(goffA1, SBA(T + 2), lofA1, bo);
    BAR(); LGKM0();
    RDB(0, bq);
    SETP(1); MQK(1, 1); SETP(0);
    sgbIL<4>();
    BAR();
  }
  {  // tail tile NT-2: stage only (NT-1).B1; drain all by end of p1
    const int T = NT - 2;
    const u32 bo = (u32)((T & 1) << 15), bq = bo ^ 0x8000u;
    stage2(goffB1, SBB(T + 1), lofB1, bq);
    BAR(); LGKM0(); RDB(2, bo); SETP(1); MQK(0, 0); SETP(0); BAR();
    BAR(); LGKM0(); RDA(4, bo); SETP(1); MQK(0, 1); SETP(0); WAIT_VM(); BAR();
    BAR(); LGKM0(); RDA(0, bq); SETP(1); MQK(1, 0); SETP(0); BAR();
    BAR(); LGKM0(); RDB(0, bq); SETP(1); MQK(1, 1); SETP(0); BAR();
  }
  {  // tail tile NT-1: no staging, no next-tile reads
    const u32 bo = (u32)(((NT - 1) & 1) << 15);
    BAR(); LGKM0(); RDB(2, bo); SETP(1); MQK(0, 0); SETP(0); BAR();
    BAR(); LGKM0(); RDA(4, bo); SETP(1); MQK(0, 1); SETP(0); BAR();
    BAR(); LGKM0(); SETP(1); MQK(1, 0); SETP(0); BAR();
    BAR(); LGKM0(); SETP(1); MQK(1, 1); SETP(0); BAR();
  }
#undef SBA
#undef SBB

  // Epilogue: stage C through LDS (4 slabs of 64 rows x 256 cols, stride 260 f32)
  float bv[4];
#pragma unroll
  for (int nj = 0; nj < 4; ++nj) bv[nj] = bias[n0 + (wc << 6) + nj * 16 + lm];
  float* Cs = (float*)SM;  // 64*260*4 = 66560 B of the 128 KB
#pragma unroll
  for (int s = 0; s < 4; ++s) {
    __syncthreads();
    if (wr == (s >> 1)) {
#pragma unroll
      for (int mi2 = 0; mi2 < 4; ++mi2) {
        const int mi = ((s & 1) << 2) + mi2;
#pragma unroll
        for (int nj = 0; nj < 4; ++nj)
#pragma unroll
          for (int rr = 0; rr < 4; ++rr)
            Cs[(mi2 * 16 + lq * 4 + rr) * 260 + (wc << 6) + nj * 16 + lm] =
                acc[mi][nj][rr] + bv[nj];
      }
    }
    __syncthreads();
#pragma unroll
    for (int w = 0; w < 8; ++w) {
      int fi = (w << 9) + tid;  // 4096 float4 chunks; each wave writes one row
      int rl = fi >> 6, cc = fi & 63;
      float4 v = *(const float4*)&Cs[rl * 260 + (cc << 2)];
      size_t grow = (size_t)(m0 + (s << 6) + rl) * N + n0 + (cc << 2);
      if constexpr (sizeof(OutT) == 2) {
        union { u16 u[4]; u64 q; } o;
        o.u[0] = f2bf(v.x); o.u[1] = f2bf(v.y); o.u[2] = f2bf(v.z); o.u[3] = f2bf(v.w);
        *(u64*)((u16*)C + grow) = o.q;
      } else {
        *(float4*)((float*)C + grow) = v;
      }
    }
  }
}

// ---------------------------------------------------------------- gates + elementwise
// GEMM part unchanged; epilogue now stages f (=norm*gx) and ga into LDS per
// 16-row slab, then all 256 threads write full coalesced lines: ga float4,
// xr/xi as u64 (4x bf16) with vectorized u64 xh re-reads.
__global__ __launch_bounds__(256, 2) void gate_elem_kernel(
    const u16* __restrict__ xh, const u16* __restrict__ wgt,
    const float* __restrict__ bgx, const float* __restrict__ bga,
    const float* __restrict__ arp,
    float* __restrict__ ga_out, u16* __restrict__ xr_out, u16* __restrict__ xi_out) {
  __shared__ __align__(16) u16 As[128 * 64];  // 16 KB
  __shared__ __align__(16) u16 Bs[256 * 64];  // 32 KB

  const int m0 = blockIdx.x << 7;
  const int blk = blockIdx.y;
  const int tid = threadIdx.x;
  const int lane = tid & 63, wid = tid >> 6;
  const int wm = (wid & 1) << 6, wn = (wid >> 1) << 6;
  const int lq = lane >> 4, lm = lane & 15;

  floatx4 acc[4][8];
#pragma unroll
  for (int i = 0; i < 4; ++i)
#pragma unroll
    for (int j = 0; j < 8; ++j) { acc[i][j].x = 0.f; acc[i][j].y = 0.f; acc[i][j].z = 0.f; acc[i][j].w = 0.f; }

  const u16* Ag = xh + (size_t)m0 * 2048 + blk * 256;  // row stride 2048
  const u16* Bg = wgt + (size_t)blk * 65536;           // [256][256] row-major

  for (int kt = 0; kt < 256; kt += 64) {
#pragma unroll
    for (int j = 0; j < 4; ++j) {
      int slot = (j << 8) + tid;
      int row = slot >> 3, ch = slot & 7;
      int gch = ch ^ (row & 7);
      cp16(Ag + (size_t)row * 2048 + kt + (gch << 3), (char*)As + slot * 16);
    }
#pragma unroll
    for (int j = 0; j < 8; ++j) {
      int slot = (j << 8) + tid;
      int row = slot >> 3, ch = slot & 7;
      int gch = ch ^ (row & 7);
      cp16(Bg + (size_t)row * 256 + kt + (gch << 3), (char*)Bs + slot * 16);
    }
    WAIT_VM();
    __syncthreads();
#pragma unroll
    for (int kk = 0; kk < 64; kk += 32) {
      const int lc = (kk >> 3) + lq;
      short8 af[4], bfr[8];
#pragma unroll
      for (int mi = 0; mi < 4; ++mi) {
        int r = wm + mi * 16 + lm;
        af[mi] = *(const short8*)&As[r * 64 + ((lc ^ (r & 7)) << 3)];
      }
#pragma unroll
      for (int ni = 0; ni < 8; ++ni) {
        int r = (ni < 4) ? (wn + ni * 16 + lm) : (128 + wn + (ni - 4) * 16 + lm);
        bfr[ni] = *(const short8*)&Bs[r * 64 + ((lc ^ (r & 7)) << 3)];
      }
#pragma unroll
      for (int mi = 0; mi < 4; ++mi)
#pragma unroll
        for (int ni = 0; ni < 8; ++ni)
          acc[mi][ni] = __builtin_amdgcn_mfma_f32_16x16x32_bf16(af[mi], bfr[ni], acc[mi][ni], 0, 0, 0);
    }
    __syncthreads();
  }

  // --- epilogue: per 16-row slab s: wave pair stages f/ga -> LDS, all write.
  float* fs = (float*)As;            // [16][132] f32 = 8448 B
  float* gas = (float*)Bs;           // [16][132] f32
  float bxv[4], bav[4], spv[4];
#pragma unroll
  for (int ni = 0; ni < 4; ++ni) {
    const int c = (blk << 7) + wn + ni * 16 + lm;
    bxv[ni] = bgx[c]; bav[ni] = bga[c];
    spv[ni] = log1pf(__expf(arp[c]));  // softplus(a_real_param)
  }
  const int blkc = blk << 7;
#pragma unroll
  for (int s = 0; s < 8; ++s) {
    __syncthreads();
    if (wm == ((s >= 4) ? 64 : 0)) {
      const int mi = s & 3;
#pragma unroll
      for (int ni = 0; ni < 4; ++ni)
#pragma unroll
        for (int r = 0; r < 4; ++r) {
          float gxv = sigmoidf_(acc[mi][ni][r] + bxv[ni]);
          float gav = sigmoidf_(acc[mi][ni + 4][r] + bav[ni]);
          float mag = __expf(-8.f * gav * spv[ni]);
          float norm = sqrtf(fmaxf(1.f - mag * mag, 0.f));
          const int rw = lq * 4 + r, cw = wn + ni * 16 + lm;
          fs[rw * 132 + cw] = norm * gxv;
          gas[rw * 132 + cw] = gav;
        }
    }
    __syncthreads();
#pragma unroll
    for (int w = 0; w < 2; ++w) {
      const int q = (w << 8) + tid;          // 512 float4-chunks: 16 rows x 32
      const int row = q >> 5, c4 = (q & 31) << 2;
      const size_t rowg = (size_t)m0 + s * 16 + row;
      const float4 fv = *(const float4*)&fs[row * 132 + c4];
      const float4 gv = *(const float4*)&gas[row * 132 + c4];
      *(float4*)&ga_out[rowg * 1024 + blkc + c4] = gv;
      union { u16 u[4]; u64 q8; } xa, xb, oa, ob;
      xa.q8 = *(const u64*)&xh[rowg * 2048 + blkc + c4];
      xb.q8 = *(const u64*)&xh[rowg * 2048 + 1024 + blkc + c4];
      oa.u[0] = f2bf(fv.x * bf2f(xa.u[0])); oa.u[1] = f2bf(fv.y * bf2f(xa.u[1]));
      oa.u[2] = f2bf(fv.z * bf2f(xa.u[2])); oa.u[3] = f2bf(fv.w * bf2f(xa.u[3]));
      ob.u[0] = f2bf(fv.x * bf2f(xb.u[0])); ob.u[1] = f2bf(fv.y * bf2f(xb.u[1]));
      ob.u[2] = f2bf(fv.z * bf2f(xb.u[2])); ob.u[3] = f2bf(fv.w * bf2f(xb.u[3]));
      *(u64*)&xr_out[rowg * 1024 + blkc + c4] = oa.q8;
      *(u64*)&xi_out[rowg * 1024 + blkc + c4] = ob.q8;
    }
  }
}

// ---------------------------------------------------------------- scan (chunk=64, 64 chunks)
// c2-vectorized: each thread owns 2 consecutive channels (8B/lane loads).
__global__ __launch_bounds__(256) void scan_pass1(
    const float* __restrict__ ga, const u16* __restrict__ xr, const u16* __restrict__ xi,
    const float* __restrict__ arp, const float* __restrict__ aip,
    float* __restrict__ Ar, float* __restrict__ Ai,
    float* __restrict__ Xr, float* __restrict__ Xi) {
  int t = blockIdx.x * 256 + threadIdx.x;  // [0, 4*64*512)
  int c2 = (t & 511) << 1;
  int chunk = (t >> 9) & 63;
  int b = t >> 15;
  float2 sp, am;
  sp.x = log1pf(__expf(arp[c2])); sp.y = log1pf(__expf(arp[c2 + 1]));
  am.x = aip[c2]; am.y = aip[c2 + 1];
  size_t base = ((size_t)b * 4096 + chunk * 64) * 1024 + c2;
  float Ar0 = 1.f, Ai0 = 0.f, Xr0 = 0.f, Xi0 = 0.f;
  float Ar1 = 1.f, Ai1 = 0.f, Xr1 = 0.f, Xi1 = 0.f;
#pragma unroll 4
  for (int i = 0; i < 64; ++i) {
    size_t idx = base + (size_t)i * 1024;
    float2 g = *(const float2*)&ga[idx];
    union { u32 w; u16 u[2]; } vr, vi;
    vr.w = *(const u32*)&xr[idx];
    vi.w = *(const u32*)&xi[idx];
    { float mag = __expf(-8.f * g.x * sp.x); float s, co; __sincosf(am.x * g.x, &s, &co);
      float ar = mag * co, ai = mag * s;
      float nxr = ar * Xr0 - ai * Xi0 + bf2f(vr.u[0]);
      float nxi = ar * Xi0 + ai * Xr0 + bf2f(vi.u[0]);
      Xr0 = nxr; Xi0 = nxi;
      float nar = ar * Ar0 - ai * Ai0, nai = ar * Ai0 + ai * Ar0;
      Ar0 = nar; Ai0 = nai; }
    { float mag = __expf(-8.f * g.y * sp.y); float s, co; __sincosf(am.y * g.y, &s, &co);
      float ar = mag * co, ai = mag * s;
      float nxr = ar * Xr1 - ai * Xi1 + bf2f(vr.u[1]);
      float nxi = ar * Xi1 + ai * Xr1 + bf2f(vi.u[1]);
      Xr1 = nxr; Xi1 = nxi;
      float nar = ar * Ar1 - ai * Ai1, nai = ar * Ai1 + ai * Ar1;
      Ar1 = nar; Ai1 = nai; }
  }
  int o = ((b << 6) + chunk) << 10;  // [b][chunk][c] layout, c fastest
  *(float2*)&Ar[o + c2] = make_float2(Ar0, Ar1);
  *(float2*)&Ai[o + c2] = make_float2(Ai0, Ai1);
  *(float2*)&Xr[o + c2] = make_float2(Xr0, Xr1);
  *(float2*)&Xi[o + c2] = make_float2(Xi0, Xi1);
}

__global__ __launch_bounds__(256) void scan_pass2(
    const float* __restrict__ Ar, const float* __restrict__ Ai,
    const float* __restrict__ Xr, const float* __restrict__ Xi,
    float* __restrict__ Hr, float* __restrict__ Hi) {
  int tid = blockIdx.x * 64 + threadIdx.x;  // [0, 4096)
  int c = tid & 1023, b = tid >> 10;
  float hr = 0.f, hi = 0.f;
  for (int j = 0; j < 64; ++j) {
    int idx = (b << 16) + (j << 10) + c;
    Hr[idx] = hr; Hi[idx] = hi;
    float ar = Ar[idx], ai = Ai[idx];
    float nhr = ar * hr - ai * hi + Xr[idx];
    float nhi = ar * hi + ai * hr + Xi[idx];
    hr = nhr; hi = nhi;
  }
}

__global__ __launch_bounds__(256) void scan_pass3(
    const float* __restrict__ ga, const u16* __restrict__ xr, const u16* __restrict__ xi,
    const float* __restrict__ arp, const float* __restrict__ aip,
    const float* __restrict__ Hr, const float* __restrict__ Hi,
    u16* __restrict__ h_out, float* __restrict__ tail) {
  int t = blockIdx.x * 256 + threadIdx.x;
  int c2 = (t & 511) << 1;
  int chunk = (t >> 9) & 63;
  int b = t >> 15;
  float2 sp, am;
  sp.x = log1pf(__expf(arp[c2])); sp.y = log1pf(__expf(arp[c2 + 1]));
  am.x = aip[c2]; am.y = aip[c2 + 1];
  size_t row0 = (size_t)b * 4096 + chunk * 64;
  size_t base = row0 * 1024 + c2;
  int o = ((b << 6) + chunk) << 10;
  float2 h0 = *(const float2*)&Hr[o + c2];
  float2 h1 = *(const float2*)&Hi[o + c2];
  float hr0 = h0.x, hr1 = h0.y, hi0 = h1.x, hi1 = h1.y;
#pragma unroll 4
  for (int i = 0; i < 64; ++i) {
    size_t idx = base + (size_t)i * 1024;
    float2 g = *(const float2*)&ga[idx];
    union { u32 w; u16 u[2]; } vr, vi, w0, w1;
    vr.w = *(const u32*)&xr[idx];
    vi.w = *(const u32*)&xi[idx];
    { float mag = __expf(-8.f * g.x * sp.x); float s, co; __sincosf(am.x * g.x, &s, &co);
      float ar = mag * co, ai = mag * s;
      float nhr = ar * hr0 - ai * hi0 + bf2f(vr.u[0]);
      float nhi = ar * hi0 + ai * hr0 + bf2f(vi.u[0]);
      hr0 = nhr; hi0 = nhi; }
    { float mag = __expf(-8.f * g.y * sp.y); float s, co; __sincosf(am.y * g.y, &s, &co);
      float ar = mag * co, ai = mag * s;
      float nhr = ar * hr1 - ai * hi1 + bf2f(vr.u[1]);
      float nhi = ar * hi1 + ai * hr1 + bf2f(vi.u[1]);
      hr1 = nhr; hi1 = nhi; }
    size_t r = row0 + i;
    w0.u[0] = f2bf(hr0); w0.u[1] = f2bf(hr1);
    w1.u[0] = f2bf(hi0); w1.u[1] = f2bf(hi1);
    *(u32*)&h_out[r * 2048 + c2] = w0.w;
    *(u32*)&h_out[r * 2048 + 1024 + c2] = w1.w;
  }
  if (chunk == 63) {  // s = 4095
    *(float2*)&tail[(size_t)b * 2048 + c2] = make_float2(hr0, hr1);
    *(float2*)&tail[(size_t)b * 2048 + 1024 + c2] = make_float2(hi0, hi1);
  }
}

// ---------------------------------------------------------------- launch
static const size_t OFF_XH = 0;            // u16 [16384][2048] (later: h)
static const size_t OFF_GA = 67108864;     // f32 [16384][1024]  (first: XB u16 [16384][2048])
static const size_t OFF_XR = 134217728;    // u16 [16384][1024]
static const size_t OFF_XI = 167772160;    // u16 [16384][1024]
static const size_t OFF_WIT = 201326592;   // u16 [2048][2048]  W_in^T
static const size_t OFF_WOT = 209715200;   // u16 [2048][2048]  W_out^T
static const size_t OFF_WGT = 218103808;   // u16 [8][256][256] gate weights^T (gx|ga)
static const size_t OFF_AGR = 219152384;   // f32 [262144] chunk aggregates
static const size_t OFF_AGI = 220200960;
static const size_t OFF_AXR = 221249536;
static const size_t OFF_AXI = 222298112;
static const size_t OFF_HPR = 223346688;   // f32 [262144] chunk prefixes
static const size_t OFF_HPI = 224395264;

extern "C" void kernel_launch(void* const* d_in, const int* in_sizes, int n_in,
                              void* d_out, int out_size, void* d_ws, size_t ws_size,
                              hipStream_t stream) {
  const float* x    = (const float*)d_in[0];
  const float* arp  = (const float*)d_in[1];
  const float* aip  = (const float*)d_in[2];
  const float* W_in = (const float*)d_in[3];
  const float* b_in = (const float*)d_in[4];
  const float* Wg_x = (const float*)d_in[5];
  const float* bg_x = (const float*)d_in[6];
  const float* Wg_a = (const float*)d_in[7];
  const float* bg_a = (const float*)d_in[8];
  const float* W_out = (const float*)d_in[9];
  const float* b_out = (const float*)d_in[10];

  char* ws = (char*)d_ws;
  u16* XH = (u16*)(ws + OFF_XH);
  u16* XB = (u16*)(ws + OFF_GA);   // bf16 copy of x; dead once GEMM1 finishes
  float* GA = (float*)(ws + OFF_GA);
  u16* XR = (u16*)(ws + OFF_XR);
  u16* XI = (u16*)(ws + OFF_XI);
  u16* WIT = (u16*)(ws + OFF_WIT);
  u16* WOT = (u16*)(ws + OFF_WOT);
  u16* WGT = (u16*)(ws + OFF_WGT);
  float* AGR = (float*)(ws + OFF_AGR);
  float* AGI = (float*)(ws + OFF_AGI);
  float* AXR = (float*)(ws + OFF_AXR);
  float* AXI = (float*)(ws + OFF_AXI);
  float* HPR = (float*)(ws + OFF_HPR);
  float* HPI = (float*)(ws + OFF_HPI);

  float* y_out = (float*)d_out;
  float* h_last = (float*)d_out + (size_t)16384 * 2048;

  // x -> bf16
  convert_f32_bf16<<<16384, 256, 0, stream>>>(x, XB, (long)16384 * 2048);

  dim3 tb(32, 8);
  transpose_f32_bf16<<<dim3(64, 64, 1), tb, 0, stream>>>(W_in, WIT, 2048, 2048, 0, 0);
  transpose_f32_bf16<<<dim3(64, 64, 1), tb, 0, stream>>>(W_out, WOT, 2048, 2048, 0, 0);
  transpose_f32_bf16<<<dim3(4, 8, 8), tb, 0, stream>>>(Wg_x, WGT, 256, 128, 32768, 65536);
  transpose_f32_bf16<<<dim3(4, 8, 8), tb, 0, stream>>>(Wg_a, WGT + 32768, 256, 128, 32768, 65536);

  // x_h = x @ W_in + b_in  (bf16 out)
  gemm256_bt_bias<u16, 2048><<<512, 512, 0, stream>>>(XB, WIT, b_in, XH, 16384, 2048);
  // gates + a/x scan inputs (overwrites XB region with GA)
  gate_elem_kernel<<<dim3(128, 8), 256, 0, stream>>>(XH, WGT, bg_x, bg_a, arp, GA, XR, XI);
  // chunked complex scan
  scan_pass1<<<512, 256, 0, stream>>>(GA, XR, XI, arp, aip, AGR, AGI, AXR, AXI);
  scan_pass2<<<64, 64, 0, stream>>>(AGR, AGI, AXR, AXI, HPR, HPI);
  scan_pass3<<<512, 256, 0, stream>>>(GA, XR, XI, arp, aip, HPR, HPI, XH /*h aliases x_h*/, h_last);
  // y = h @ W_out + b_out  (fp32 out)
  gemm256_bt_bias<float, 2048><<<512, 512, 0, stream>>>(XH, WOT, b_out, y_out, 16384, 2048);
}